// Round 16
// baseline (378.052 us; speedup 1.0000x reference)
//
#include <hip/hip_runtime.h>
#include <math.h>

#define NN 4096
#define HID 256
#define MD 32
#define NH 8
#define SCALE 0.17677669529663687f  // 1/sqrt(32)
#define QSCALE 0.25503164588f       // SCALE * log2(e)

typedef float f32x4 __attribute__((ext_vector_type(4)));
typedef short bf16x8 __attribute__((ext_vector_type(8)));
typedef _Float16 f16x8 __attribute__((ext_vector_type(8)));
typedef _Float16 f16x4 __attribute__((ext_vector_type(4)));
typedef _Float16 f16x2 __attribute__((ext_vector_type(2)));

#define EXP2(x) __builtin_amdgcn_exp2f(x)   // raw v_exp_f32 (D = 2^S0)

__device__ inline unsigned int bfr(float x) {             // f32 -> bf16 bits (RNE)
    unsigned int u = __float_as_uint(x);
    return (u + 0x7fffu + ((u >> 16) & 1u)) >> 16;
}
__device__ inline unsigned int pkbf(float a, float b) {
    return bfr(a) | (bfr(b) << 16);
}
__device__ inline unsigned int pkhf(float a, float b) {   // 2 x f16 (RNE)
    union { f16x2 h; unsigned int u; } z;
    z.h = (f16x2){(_Float16)a, (_Float16)b};
    return z.u;
}
__device__ inline unsigned int spread4(unsigned int x) {  // bit i -> bit 4i
    x = (x | (x << 12)) & 0x000F000Fu;
    x = (x | (x << 6))  & 0x03030303u;
    x = (x | (x << 3))  & 0x11111111u;
    return x;
}

// -------- prep: pack NF -> bf16, transpose Wq/Wk -> bf16 Wt[c][k] ---------
__global__ __launch_bounds__(256) void prep_kernel(
    const float* __restrict__ nf, const float* __restrict__ Wq,
    const float* __restrict__ Wk, unsigned short* __restrict__ NFb,
    unsigned short* __restrict__ Wt)
{
    __shared__ __align__(16) float lds[64 * 65];
    const int b = blockIdx.x, t = threadIdx.x;
    if (b < 512) {
        const float* src = nf + (size_t)b * 2048 + t * 8;
        float4 a = ((const float4*)src)[0];
        float4 c = ((const float4*)src)[1];
        uint4 o;
        o.x = pkbf(a.x, a.y); o.y = pkbf(a.z, a.w);
        o.z = pkbf(c.x, c.y); o.w = pkbf(c.z, c.w);
        *(uint4*)(NFb + (size_t)b * 2048 + t * 8) = o;
        return;
    }
    const int b2 = b - 512;
    const int mat = b2 >> 4, tile = b2 & 15;
    const int k0 = (tile >> 2) * 64, c0 = (tile & 3) * 64;
    const float* W = mat ? Wk : Wq;
    #pragma unroll
    for (int i = 0; i < 16; ++i) {
        int idx = i * 256 + t;
        int row = idx >> 4, c4 = idx & 15;
        float4 v = *(const float4*)(W + (size_t)(k0 + row) * 256 + c0 + c4 * 4);
        lds[row * 65 + c4 * 4 + 0] = v.x;
        lds[row * 65 + c4 * 4 + 1] = v.y;
        lds[row * 65 + c4 * 4 + 2] = v.z;
        lds[row * 65 + c4 * 4 + 3] = v.w;
    }
    __syncthreads();
    #pragma unroll
    for (int i = 0; i < 2; ++i) {
        int j = i * 256 + t;
        int c_loc = j >> 3, kq = j & 7;
        uint4 o;
        o.x = pkbf(lds[(kq * 8 + 0) * 65 + c_loc], lds[(kq * 8 + 1) * 65 + c_loc]);
        o.y = pkbf(lds[(kq * 8 + 2) * 65 + c_loc], lds[(kq * 8 + 3) * 65 + c_loc]);
        o.z = pkbf(lds[(kq * 8 + 4) * 65 + c_loc], lds[(kq * 8 + 5) * 65 + c_loc]);
        o.w = pkbf(lds[(kq * 8 + 6) * 65 + c_loc], lds[(kq * 8 + 7) * 65 + c_loc]);
        *(uint4*)(Wt + (size_t)mat * 65536 + (size_t)(c0 + c_loc) * 256 + k0 + kq * 8) = o;
    }
}

// -------- Q,K projection via MFMA (outT[c][n] = W^T . NF^T) ---------------
__global__ __launch_bounds__(256, 4) void proj_mfma(
    const unsigned short* __restrict__ NFb, const unsigned short* __restrict__ Wt,
    const float* __restrict__ bq, const float* __restrict__ bk,
    unsigned short* __restrict__ Qb, unsigned short* __restrict__ Kb)
{
    const int b = blockIdx.x;
    const int isK = b >> 7, nb = b & 127;
    const unsigned short* Wm = Wt + (size_t)isK * 65536;
    const float* bias = isK ? bk : bq;
    unsigned short* outp = isK ? Kb : Qb;
    const int t = threadIdx.x, w = t >> 6, l = t & 63;
    const int g = l >> 4, q = l & 15;
    const int n0 = nb * 32 + (w & 1) * 16;
    const int chalf = w >> 1;

    f32x4 acc[8];
    #pragma unroll
    for (int ct = 0; ct < 8; ++ct) acc[ct] = (f32x4){0.f, 0.f, 0.f, 0.f};

    #pragma unroll
    for (int kc = 0; kc < 8; ++kc) {
        bf16x8 bfrag = *(const bf16x8*)(NFb + (size_t)(n0 + q) * 256 + kc * 32 + g * 8);
        #pragma unroll
        for (int ct = 0; ct < 8; ++ct) {
            int c = (chalf * 8 + ct) * 16 + q;
            bf16x8 afrag = *(const bf16x8*)(Wm + (size_t)c * 256 + kc * 32 + g * 8);
            acc[ct] = __builtin_amdgcn_mfma_f32_16x16x32_bf16(afrag, bfrag, acc[ct], 0, 0, 0);
        }
    }
    const float sc = isK ? 1.0f : QSCALE;
    const int n = n0 + q;
    #pragma unroll
    for (int ct = 0; ct < 8; ++ct) {
        int c0 = (chalf * 8 + ct) * 16 + 4 * g;
        float4 bv = *(const float4*)(bias + c0);
        float v0 = (acc[ct][0] + bv.x) * sc;
        float v1 = (acc[ct][1] + bv.y) * sc;
        float v2 = (acc[ct][2] + bv.z) * sc;
        float v3 = (acc[ct][3] + bv.w) * sc;
        uint2 o;
        o.x = pkbf(v0, v1); o.y = pkbf(v2, v3);
        int h = c0 >> 5, d = c0 & 31;
        *(uint2*)(outp + ((size_t)h * NN + n) * 32 + d) = o;
    }
}

// -------- V projection (KD=32, tiny) --------------------------------------
__global__ __launch_bounds__(256) void proj_v(
    const float* __restrict__ msg, const float* __restrict__ Wv,
    const float* __restrict__ bv, float* __restrict__ Vo)
{
    __shared__ __align__(16) float in_lds[32 * 32];
    const int nb = blockIdx.x;
    const int t = threadIdx.x;
    ((float4*)in_lds)[t] = ((const float4*)(msg + (size_t)nb * 1024))[t];
    __syncthreads();
    float acc[32];
    #pragma unroll
    for (int r = 0; r < 32; ++r) acc[r] = 0.f;
    #pragma unroll 8
    for (int k = 0; k < 32; ++k) {
        float w = Wv[k * 256 + t];
        #pragma unroll
        for (int r = 0; r < 32; ++r) acc[r] += in_lds[r * 32 + k] * w;
    }
    const float bb = bv[t];
    #pragma unroll
    for (int r = 0; r < 32; ++r)
        Vo[(size_t)(nb * 32 + r) * 256 + t] = acc[r] + bb;
}

// ------------- adjacency bitmask: vectorized loads, OLD bit layout --------
__global__ __launch_bounds__(256) void abit_kernel(
    const int* __restrict__ adj, unsigned int* __restrict__ ab32)
{
    const int w = threadIdx.x >> 6, lane = threadIdx.x & 63;
    const int n = blockIdx.x * 4 + w;
    const int* base = adj + (size_t)n * NN;
    for (int it = 0; it < 16; ++it) {
        int4 v = *(const int4*)(base + it * 256 + lane * 4);
        unsigned long long b0 = __ballot(v.x != 0);
        unsigned long long b1 = __ballot(v.y != 0);
        unsigned long long b2 = __ballot(v.z != 0);
        unsigned long long b3 = __ballot(v.w != 0);
        if (lane < 8) {
            unsigned int sh = lane * 8;
            unsigned int B0 = (unsigned int)((b0 >> sh) & 0xffULL);
            unsigned int B1 = (unsigned int)((b1 >> sh) & 0xffULL);
            unsigned int B2 = (unsigned int)((b2 >> sh) & 0xffULL);
            unsigned int B3 = (unsigned int)((b3 >> sh) & 0xffULL);
            unsigned int wd = spread4(B0) | (spread4(B1) << 1)
                            | (spread4(B2) << 2) | (spread4(B3) << 3);
            ab32[(size_t)n * 128 + it * 8 + lane] = wd;
        }
    }
}

// -------- V f32 -> transposed Vt[h][d][m'] (permuted granules, r15) -------
__global__ __launch_bounds__(256) void pack_vt(
    const float* __restrict__ Vf, unsigned short* __restrict__ Vt, int usef16)
{
    __shared__ __align__(16) float lds[128 * 33];
    const int h = blockIdx.x >> 5, mt = blockIdx.x & 31;
    const int t = threadIdx.x;
    for (int k = 0; k < 4; ++k) {
        int flat = k * 256 + t;
        int row = flat >> 3, c4 = flat & 7;
        float4 v = *(const float4*)(Vf + (size_t)(mt * 128 + row) * 256 + h * 32 + c4 * 4);
        lds[row * 33 + c4 * 4 + 0] = v.x;
        lds[row * 33 + c4 * 4 + 1] = v.y;
        lds[row * 33 + c4 * 4 + 2] = v.z;
        lds[row * 33 + c4 * 4 + 3] = v.w;
    }
    __syncthreads();
    if (usef16) {
        #pragma unroll
        for (int it = 0; it < 2; ++it) {
            int jb = it * 256 + t;
            int d = jb >> 4, chs = jb & 15;
            int chunk = chs >> 2, seg = chs & 3;
            int mb = chunk * 32 + seg * 4;
            uint4 o;
            o.x = pkhf(lds[(mb + 0) * 33 + d],  lds[(mb + 1) * 33 + d]);
            o.y = pkhf(lds[(mb + 2) * 33 + d],  lds[(mb + 3) * 33 + d]);
            o.z = pkhf(lds[(mb + 16) * 33 + d], lds[(mb + 17) * 33 + d]);
            o.w = pkhf(lds[(mb + 18) * 33 + d], lds[(mb + 19) * 33 + d]);
            *(uint4*)(Vt + ((size_t)(h * 32 + d)) * NN + mt * 128 + chunk * 32 + seg * 8) = o;
        }
    } else {
        const int d = t >> 3, mq = t & 7;
        #pragma unroll
        for (int k = 0; k < 2; ++k) {
            int m0 = mq * 16 + k * 8;
            uint4 o;
            o.x = pkbf(lds[(m0 + 0) * 33 + d], lds[(m0 + 1) * 33 + d]);
            o.y = pkbf(lds[(m0 + 2) * 33 + d], lds[(m0 + 3) * 33 + d]);
            o.z = pkbf(lds[(m0 + 4) * 33 + d], lds[(m0 + 5) * 33 + d]);
            o.w = pkbf(lds[(m0 + 6) * 33 + d], lds[(m0 + 7) * 33 + d]);
            *(uint4*)(Vt + ((size_t)(h * 32 + d)) * NN + mt * 128 + m0) = o;
        }
    }
}

// ======================= STAGED SWEEPS ====================================
__global__ __launch_bounds__(256, 4) void sweep1s_kernel(
    const unsigned short* __restrict__ Qb, const unsigned short* __restrict__ Kb,
    const unsigned int* __restrict__ abit, float* __restrict__ Lpart)
{
    __shared__ __align__(16) char smem[32768];
    const int nquad = blockIdx.x, msg = blockIdx.y;
    const int t = threadIdx.x;
    const int w = t >> 6, l = t & 63;
    const int g = l >> 4, q = l & 15;
    const int n0 = nquad * 64 + w * 16;
    const int m0 = msg * 512;
    const int fq = (q >> 1) & 3;

    const char* gsrc[4];
    #pragma unroll
    for (int i = 0; i < 4; ++i) {
        int s = i * 256 + t;
        int tile = s >> 7;
        int r = (s >> 2) & 31;
        int gr = (s & 3) ^ ((r >> 1) & 3);
        gsrc[i] = (const char*)Kb + (((size_t)tile * NN + m0 + r) * 64 + gr * 16);
    }
    const unsigned int* abrow = abit + (size_t)(n0 + q) * 128 + msg * 16;

    bf16x8 qf[8];
    #pragma unroll
    for (int h = 0; h < 8; ++h)
        qf[h] = *(const bf16x8*)(Qb + (((size_t)h * NN + n0 + q) << 5) + g * 8);
    float lacc[8];
    #pragma unroll
    for (int h = 0; h < 8; ++h) lacc[h] = 0.f;

    #pragma unroll
    for (int i = 0; i < 4; ++i)
        __builtin_amdgcn_global_load_lds((const unsigned int*)gsrc[i],
            (unsigned int*)(smem + i * 4096 + w * 1024), 16, 0, 0);
    unsigned int wb = abrow[0];
    unsigned int wbn = 0;
    __syncthreads();

    for (int c = 0; c < 16; ++c) {
        const char* cur = smem + (c & 1) * 16384;
        if (c < 15) {
            wbn = abrow[c + 1];
            char* nxt = smem + ((c & 1) ^ 1) * 16384;
            #pragma unroll
            for (int i = 0; i < 4; ++i)
                __builtin_amdgcn_global_load_lds(
                    (const unsigned int*)(gsrc[i] + (size_t)(c + 1) * 2048),
                    (unsigned int*)(nxt + i * 4096 + w * 1024), 16, 0, 0);
        }
        #pragma unroll
        for (int h = 0; h < 8; ++h) {
            const int ko = h * 2048 + q * 64 + ((g ^ fq) << 4);
            bf16x8 ka0 = *(const bf16x8*)(cur + ko);
            bf16x8 ka1 = *(const bf16x8*)(cur + ko + 1024);
            f32x4 z = {0.f, 0.f, 0.f, 0.f};
            f32x4 s0 = __builtin_amdgcn_mfma_f32_16x16x32_bf16(ka0, qf[h], z, 0, 0, 0);
            f32x4 s1 = __builtin_amdgcn_mfma_f32_16x16x32_bf16(ka1, qf[h], z, 0, 0, 0);
            #pragma unroll
            for (int r = 0; r < 4; ++r) {
                float e0 = EXP2(s0[r]);
                float e1 = EXP2(s1[r]);
                lacc[h] += ((wb >> (4 * g + r)) & 1u) ? e0 : 0.f;
                lacc[h] += ((wb >> (16 + 4 * g + r)) & 1u) ? e1 : 0.f;
            }
        }
        __syncthreads();
        wb = wbn;
    }
    #pragma unroll
    for (int h = 0; h < 8; ++h) {
        float v = lacc[h];
        v += __shfl_xor(v, 16);
        v += __shfl_xor(v, 32);
        if (g == 0) Lpart[(size_t)msg * 32768 + h * NN + n0 + q] = v;
    }
}

// sweep2s: K staged (16KB x2 buffers, 4 blocks/CU); V read DIRECTLY from
// L2-resident permuted Vt (2MB total, no swizzle needed on global reads).
// Mechanism: Vt L2-fits (guide lesson: staging L2-fit data is overhead);
// halved LDS doubles blocks/CU -> 2x TLP at unchanged per-wave ILP.
__global__ __launch_bounds__(256, 4) void sweep2s_kernel(
    const unsigned short* __restrict__ Qb, const unsigned short* __restrict__ Kb,
    const unsigned short* __restrict__ Vt, const unsigned int* __restrict__ abit,
    const float* __restrict__ Linv, float* __restrict__ Opart,
    float* __restrict__ amean)
{
    __shared__ __align__(16) char smem[32768];
    const int nquad = blockIdx.x, msg = blockIdx.y;
    const int t = threadIdx.x;
    const int w = t >> 6, l = t & 63;
    const int g = l >> 4, q = l & 15;
    const int n0 = nquad * 64 + w * 16;
    const int m0 = msg * 512;
    const int fq = (q >> 1) & 3;
    const _Float16* VtF = (const _Float16*)Vt;

    const char* gsrc[4];
    #pragma unroll
    for (int i = 0; i < 4; ++i) {
        int s = i * 256 + t;
        int tile = s >> 7;
        int r = (s >> 2) & 31;
        int gr = (s & 3) ^ ((r >> 1) & 3);
        gsrc[i] = (const char*)Kb + (((size_t)tile * NN + m0 + r) * 64 + gr * 16);
    }
    const unsigned int* abrow = abit + (size_t)(n0 + q) * 128 + msg * 16;

    bf16x8 qf[8];
    float rL[8];
    #pragma unroll
    for (int h = 0; h < 8; ++h) {
        qf[h] = *(const bf16x8*)(Qb + (((size_t)h * NN + n0 + q) << 5) + g * 8);
        rL[h] = Linv[h * NN + n0 + q];
    }
    f32x4 o[8][2];
    #pragma unroll
    for (int h = 0; h < 8; ++h) {
        o[h][0] = (f32x4){0.f, 0.f, 0.f, 0.f};
        o[h][1] = (f32x4){0.f, 0.f, 0.f, 0.f};
    }

    #pragma unroll
    for (int i = 0; i < 4; ++i)
        __builtin_amdgcn_global_load_lds((const unsigned int*)gsrc[i],
            (unsigned int*)(smem + i * 4096 + w * 1024), 16, 0, 0);
    unsigned int wb = abrow[0];
    unsigned int wbn = 0;
    __syncthreads();

    for (int c = 0; c < 16; ++c) {
        const char* cur = smem + (c & 1) * 16384;
        if (c < 15) {
            wbn = abrow[c + 1];
            char* nxt = smem + ((c & 1) ^ 1) * 16384;
            #pragma unroll
            for (int i = 0; i < 4; ++i)
                __builtin_amdgcn_global_load_lds(
                    (const unsigned int*)(gsrc[i] + (size_t)(c + 1) * 2048),
                    (unsigned int*)(nxt + i * 4096 + w * 1024), 16, 0, 0);
        }
        const int mb = m0 + c * 32;
        float am[8];
        #pragma unroll
        for (int r = 0; r < 8; ++r) am[r] = 0.f;

        #pragma unroll
        for (int h = 0; h < 8; ++h) {
            const int ko = h * 2048 + q * 64 + ((g ^ fq) << 4);
            bf16x8 ka0 = *(const bf16x8*)(cur + ko);
            bf16x8 ka1 = *(const bf16x8*)(cur + ko + 1024);
            // V direct from global (permuted Vt, linear address, no swizzle)
            const _Float16* vg = VtF + ((size_t)(h * 32 + q)) * NN + mb + g * 8;
            f16x8 lo8 = *(const f16x8*)(vg);                 // d = q
            f16x8 hi8 = *(const f16x8*)(vg + (size_t)16 * NN); // d = 16+q
            f16x4 va00 = __builtin_shufflevector(lo8, lo8, 0, 1, 2, 3);
            f16x4 va10 = __builtin_shufflevector(lo8, lo8, 4, 5, 6, 7);
            f16x4 va01 = __builtin_shufflevector(hi8, hi8, 0, 1, 2, 3);
            f16x4 va11 = __builtin_shufflevector(hi8, hi8, 4, 5, 6, 7);
            f32x4 z = {0.f, 0.f, 0.f, 0.f};
            f32x4 s0 = __builtin_amdgcn_mfma_f32_16x16x32_bf16(ka0, qf[h], z, 0, 0, 0);
            f32x4 s1 = __builtin_amdgcn_mfma_f32_16x16x32_bf16(ka1, qf[h], z, 0, 0, 0);
            float pn[8];
            #pragma unroll
            for (int r = 0; r < 4; ++r) {
                float e0 = EXP2(s0[r]) * rL[h];
                float e1 = EXP2(s1[r]) * rL[h];
                pn[r]     = ((wb >> (4 * g + r)) & 1u) ? e0 : 0.f;
                pn[4 + r] = ((wb >> (16 + 4 * g + r)) & 1u) ? e1 : 0.f;
                am[r] += pn[r];
                am[4 + r] += pn[4 + r];
            }
            union { unsigned int u[2]; f16x4 v; } pA, pB;
            pA.u[0] = pkhf(pn[0], pn[1]); pA.u[1] = pkhf(pn[2], pn[3]);
            pB.u[0] = pkhf(pn[4], pn[5]); pB.u[1] = pkhf(pn[6], pn[7]);
            o[h][0] = __builtin_amdgcn_mfma_f32_16x16x16f16(va00, pA.v, o[h][0], 0, 0, 0);
            o[h][1] = __builtin_amdgcn_mfma_f32_16x16x16f16(va01, pA.v, o[h][1], 0, 0, 0);
            o[h][0] = __builtin_amdgcn_mfma_f32_16x16x16f16(va10, pB.v, o[h][0], 0, 0, 0);
            o[h][1] = __builtin_amdgcn_mfma_f32_16x16x16f16(va11, pB.v, o[h][1], 0, 0, 0);
        }
        float4 a0, a1;
        a0.x = am[0] * 0.125f; a0.y = am[1] * 0.125f;
        a0.z = am[2] * 0.125f; a0.w = am[3] * 0.125f;
        a1.x = am[4] * 0.125f; a1.y = am[5] * 0.125f;
        a1.z = am[6] * 0.125f; a1.w = am[7] * 0.125f;
        *(float4*)(amean + (size_t)(n0 + q) * NN + mb + 4 * g) = a0;
        *(float4*)(amean + (size_t)(n0 + q) * NN + mb + 16 + 4 * g) = a1;
        __syncthreads();
        wb = wbn;
    }

    float* op = Opart + ((size_t)msg * NN + n0 + q) * 256;
    #pragma unroll
    for (int h = 0; h < 8; ++h) {
        *(f32x4*)(op + h * 32 + 4 * g) = o[h][0];
        *(f32x4*)(op + h * 32 + 16 + 4 * g) = o[h][1];
    }
}

// ======================= OLD SWEEPS (path B fallback) =====================
__global__ __launch_bounds__(256, 4) void sweep1_old(
    const unsigned short* __restrict__ Qb, const unsigned short* __restrict__ Kb,
    const unsigned int* __restrict__ abit, float* __restrict__ Lpart)
{
    const int ntile = blockIdx.x, msg = blockIdx.y;
    const int t = threadIdx.x;
    const int w = t >> 6, l = t & 63;
    const int g = l >> 4, q = l & 15;
    const int ms = msg * 4 + w;
    const int n0 = ntile * 16;
    const int mbase = ms * 256;
    bf16x8 qf[8];
    #pragma unroll
    for (int h = 0; h < 8; ++h)
        qf[h] = *(const bf16x8*)(Qb + (((size_t)h * NN + n0 + q) << 5) + g * 8);
    float lacc[8];
    #pragma unroll
    for (int h = 0; h < 8; ++h) lacc[h] = 0.f;
    for (int ch = 0; ch < 8; ++ch) {
        const int mb = mbase + ch * 32;
        const unsigned int wbits = abit[(size_t)(n0 + q) * 128 + (mb >> 5)];
        #pragma unroll
        for (int h = 0; h < 8; ++h) {
            bf16x8 ka0 = *(const bf16x8*)(Kb + (((size_t)h * NN + mb + q) << 5) + g * 8);
            bf16x8 ka1 = *(const bf16x8*)(Kb + (((size_t)h * NN + mb + 16 + q) << 5) + g * 8);
            f32x4 z = {0.f, 0.f, 0.f, 0.f};
            f32x4 s0 = __builtin_amdgcn_mfma_f32_16x16x32_bf16(ka0, qf[h], z, 0, 0, 0);
            f32x4 s1 = __builtin_amdgcn_mfma_f32_16x16x32_bf16(ka1, qf[h], z, 0, 0, 0);
            #pragma unroll
            for (int r = 0; r < 4; ++r) {
                float e0 = EXP2(s0[r]);
                float e1 = EXP2(s1[r]);
                lacc[h] += ((wbits >> (4 * g + r)) & 1u) ? e0 : 0.f;
                lacc[h] += ((wbits >> (16 + 4 * g + r)) & 1u) ? e1 : 0.f;
            }
        }
    }
    #pragma unroll
    for (int h = 0; h < 8; ++h) {
        float v = lacc[h];
        v += __shfl_xor(v, 16);
        v += __shfl_xor(v, 32);
        if (g == 0) Lpart[(size_t)ms * 32768 + h * NN + n0 + q] = v;
    }
}

__global__ __launch_bounds__(256, 2) void sweep2_old(
    const unsigned short* __restrict__ Qb, const unsigned short* __restrict__ Kb,
    const unsigned short* __restrict__ Vt, const unsigned int* __restrict__ abit,
    const float* __restrict__ Linv, float* __restrict__ Opart,
    float* __restrict__ amean)
{
    __shared__ __align__(16) float Ow[2 * 16 * 260];
    const int ntile = blockIdx.x, msg = blockIdx.y;
    const int t = threadIdx.x;
    const int w = t >> 6, l = t & 63;
    const int g = l >> 4, q = l & 15;
    const int ms = msg * 4 + w;
    const int n0 = ntile * 16;
    const int mbase = ms * 256;
    const int baddr = (q + (g & 1) * 32) << 2;
    const bool hi = (g >= 2);
    bf16x8 qf[8];
    float rL[8];
    #pragma unroll
    for (int h = 0; h < 8; ++h) {
        qf[h] = *(const bf16x8*)(Qb + (((size_t)h * NN + n0 + q) << 5) + g * 8);
        rL[h] = Linv[h * NN + n0 + q];
    }
    f32x4 o[8][2];
    #pragma unroll
    for (int h = 0; h < 8; ++h) {
        o[h][0] = (f32x4){0.f, 0.f, 0.f, 0.f};
        o[h][1] = (f32x4){0.f, 0.f, 0.f, 0.f};
    }
    for (int ch = 0; ch < 8; ++ch) {
        const int mb = mbase + ch * 32;
        const unsigned int wbits = abit[(size_t)(n0 + q) * 128 + (mb >> 5)];
        float am[8];
        #pragma unroll
        for (int r = 0; r < 8; ++r) am[r] = 0.f;
        #pragma unroll
        for (int h = 0; h < 8; ++h) {
            bf16x8 ka0 = *(const bf16x8*)(Kb + (((size_t)h * NN + mb + q) << 5) + g * 8);
            bf16x8 ka1 = *(const bf16x8*)(Kb + (((size_t)h * NN + mb + 16 + q) << 5) + g * 8);
            f32x4 z = {0.f, 0.f, 0.f, 0.f};
            f32x4 s0 = __builtin_amdgcn_mfma_f32_16x16x32_bf16(ka0, qf[h], z, 0, 0, 0);
            f32x4 s1 = __builtin_amdgcn_mfma_f32_16x16x32_bf16(ka1, qf[h], z, 0, 0, 0);
            float pn[8];
            #pragma unroll
            for (int r = 0; r < 4; ++r) {
                float e0 = EXP2(s0[r]) * rL[h];
                float e1 = EXP2(s1[r]) * rL[h];
                pn[r]     = ((wbits >> (4 * g + r)) & 1u) ? e0 : 0.f;
                pn[4 + r] = ((wbits >> (16 + 4 * g + r)) & 1u) ? e1 : 0.f;
                am[r] += pn[r];
                am[4 + r] += pn[4 + r];
            }
            unsigned int pk0 = pkbf(pn[0], pn[1]);
            unsigned int pk1 = pkbf(pn[2], pn[3]);
            unsigned int pk2 = pkbf(pn[4], pn[5]);
            unsigned int pk3 = pkbf(pn[6], pn[7]);
            int r0lo = __builtin_amdgcn_ds_bpermute(baddr,      (int)pk0);
            int r0hi = __builtin_amdgcn_ds_bpermute(baddr,      (int)pk2);
            int r1lo = __builtin_amdgcn_ds_bpermute(baddr,      (int)pk1);
            int r1hi = __builtin_amdgcn_ds_bpermute(baddr,      (int)pk3);
            int r2lo = __builtin_amdgcn_ds_bpermute(baddr + 64, (int)pk0);
            int r2hi = __builtin_amdgcn_ds_bpermute(baddr + 64, (int)pk2);
            int r3lo = __builtin_amdgcn_ds_bpermute(baddr + 64, (int)pk1);
            int r3hi = __builtin_amdgcn_ds_bpermute(baddr + 64, (int)pk3);
            union { unsigned int u[4]; bf16x8 v; } pu;
            pu.u[0] = (unsigned int)(hi ? r0hi : r0lo);
            pu.u[1] = (unsigned int)(hi ? r1hi : r1lo);
            pu.u[2] = (unsigned int)(hi ? r2hi : r2lo);
            pu.u[3] = (unsigned int)(hi ? r3hi : r3lo);
            bf16x8 va0 = *(const bf16x8*)(Vt + ((size_t)(h * 32 + q)) * NN + mb + g * 8);
            bf16x8 va1 = *(const bf16x8*)(Vt + ((size_t)(h * 32 + 16 + q)) * NN + mb + g * 8);
            o[h][0] = __builtin_amdgcn_mfma_f32_16x16x32_bf16(va0, pu.v, o[h][0], 0, 0, 0);
            o[h][1] = __builtin_amdgcn_mfma_f32_16x16x32_bf16(va1, pu.v, o[h][1], 0, 0, 0);
        }
        float4 a0, a1;
        a0.x = am[0] * 0.125f; a0.y = am[1] * 0.125f;
        a0.z = am[2] * 0.125f; a0.w = am[3] * 0.125f;
        a1.x = am[4] * 0.125f; a1.y = am[5] * 0.125f;
        a1.z = am[6] * 0.125f; a1.w = am[7] * 0.125f;
        *(float4*)(amean + (size_t)(n0 + q) * NN + mb + 4 * g) = a0;
        *(float4*)(amean + (size_t)(n0 + q) * NN + mb + 16 + 4 * g) = a1;
    }
    if (w < 2) {
        #pragma unroll
        for (int h = 0; h < 8; ++h)
            #pragma unroll
            for (int dt = 0; dt < 2; ++dt)
                *(f32x4*)&Ow[w * 4160 + q * 260 + h * 32 + dt * 16 + 4 * g] = o[h][dt];
    }
    __syncthreads();
    if (w >= 2) {
        #pragma unroll
        for (int h = 0; h < 8; ++h)
            #pragma unroll
            for (int dt = 0; dt < 2; ++dt) {
                f32x4* p = (f32x4*)&Ow[(w - 2) * 4160 + q * 260 + h * 32 + dt * 16 + 4 * g];
                *p = *p + o[h][dt];
            }
    }
    __syncthreads();
    for (int i = t; i < 4096; i += 256) {
        int n = i >> 8, c2 = i & 255;
        float v = Ow[n * 260 + c2] + Ow[4160 + n * 260 + c2];
        Opart[((size_t)msg * NN + n0 + n) * 256 + c2] = v;
    }
}

// ---------------- Linv ----------------------------------------------------
__global__ __launch_bounds__(256) void linv_kernel(
    const float* __restrict__ Lpart, float* __restrict__ Linv, int nms)
{
    int i = blockIdx.x * 256 + threadIdx.x;
    float s = 0.f;
    for (int ms = 0; ms < nms; ++ms) s += Lpart[(size_t)ms * 32768 + i];
    Linv[i] = 1.0f / s;
}

// -------- finalize: routed = (sum_ms Opart) @ Wo + bo ---------------------
__global__ __launch_bounds__(256) void final_kernel(
    const float* __restrict__ Opart, const float* __restrict__ Wo,
    const float* __restrict__ bo, float* __restrict__ routed, int nms)
{
    __shared__ __align__(16) float Osum[16 * 260];
    __shared__ __align__(16) float WoT[32 * 260];
    const int nb = blockIdx.x, t = threadIdx.x;
    for (int i4 = t; i4 < 2048; i4 += 256) {
        int k = i4 >> 3, j4b = i4 & 7;
        float4 v = *(const float4*)(Wo + k * 32 + j4b * 4);
        WoT[(j4b * 4 + 0) * 260 + k] = v.x;
        WoT[(j4b * 4 + 1) * 260 + k] = v.y;
        WoT[(j4b * 4 + 2) * 260 + k] = v.z;
        WoT[(j4b * 4 + 3) * 260 + k] = v.w;
    }
    for (int i = t; i < 4096; i += 256) {
        int r = i >> 8, c = i & 255;
        const float* ap = Opart + ((size_t)(nb * 16 + r)) * 256 + c;
        float s = 0.f;
        for (int ms = 0; ms < nms; ++ms) s += ap[(size_t)ms * 1048576];
        Osum[r * 260 + c] = s;
    }
    __syncthreads();
    const int rh = t >> 5, j = t & 31;
    const float bj = bo[j];
    #pragma unroll
    for (int rr = 0; rr < 2; ++rr) {
        int r = rh * 2 + rr;
        float a0 = 0.f, a1 = 0.f;
        #pragma unroll
        for (int i4 = 0; i4 < 64; i4 += 2) {
            float4 ov = *(const float4*)&Osum[r * 260 + i4 * 4];
            float4 wv = *(const float4*)&WoT[j * 260 + i4 * 4];
            a0 += ov.x * wv.x + ov.y * wv.y + ov.z * wv.z + ov.w * wv.w;
            float4 ov2 = *(const float4*)&Osum[r * 260 + i4 * 4 + 4];
            float4 wv2 = *(const float4*)&WoT[j * 260 + i4 * 4 + 4];
            a1 += ov2.x * wv2.x + ov2.y * wv2.y + ov2.z * wv2.z + ov2.w * wv2.w;
        }
        routed[(size_t)(nb * 16 + r) * 32 + j] = a0 + a1 + bj;
    }
}

extern "C" void kernel_launch(void* const* d_in, const int* in_sizes, int n_in,
                              void* d_out, int out_size, void* d_ws, size_t ws_size,
                              hipStream_t stream) {
    const float* nf  = (const float*)d_in[0];
    const float* msg = (const float*)d_in[1];
    const int*   adj = (const int*)d_in[2];
    const float* Wq  = (const float*)d_in[3];
    const float* bq  = (const float*)d_in[4];
    const float* Wk  = (const float*)d_in[5];
    const float* bk  = (const float*)d_in[6];
    const float* Wv  = (const float*)d_in[7];
    const float* bv  = (const float*)d_in[8];
    const float* Wo  = (const float*)d_in[9];
    const float* bo  = (const float*)d_in[10];

    float* routed = (float*)d_out;
    float* amean  = (float*)d_out + (size_t)NN * MD;
    float* ws = (float*)d_ws;

    const bool bigws = (ws_size >= 43122688ull);

    if (bigws) {
        float* Vf = ws;                                     // dead before sweep2s
        unsigned short* NFb = (unsigned short*)(ws + 2097152);
        unsigned short* Wt  = (unsigned short*)(ws + 2621440);
        float* Opart = ws;                                  // 8 x 1M floats
        unsigned short* Qb = (unsigned short*)(ws + 8388608);
        unsigned short* Kb = (unsigned short*)(ws + 8912896);
        unsigned short* Vt = (unsigned short*)(ws + 9437184);
        unsigned int*   ab32 = (unsigned int*)(ws + 9961472);
        float* Lpart = ws + 10485760;
        float* Linv  = ws + 10747904;

        prep_kernel<<<544, 256, 0, stream>>>(nf, Wq, Wk, NFb, Wt);
        proj_mfma<<<256, 256, 0, stream>>>(NFb, Wt, bq, bk, Qb, Kb);
        proj_v<<<128, 256, 0, stream>>>(msg, Wv, bv, Vf);
        abit_kernel<<<1024, 256, 0, stream>>>(adj, ab32);
        pack_vt<<<256, 256, 0, stream>>>(Vf, Vt, 1);
        sweep1s_kernel<<<dim3(64, 8), 256, 0, stream>>>(Qb, Kb, ab32, Lpart);
        linv_kernel<<<128, 256, 0, stream>>>(Lpart, Linv, 8);
        sweep2s_kernel<<<dim3(64, 8), 256, 0, stream>>>(Qb, Kb, Vt, ab32, Linv, Opart, amean);
        final_kernel<<<256, 256, 0, stream>>>(Opart, Wo, bo, routed, 8);
    } else {
        float* Vf = ws;
        unsigned short* NFb = (unsigned short*)(ws + 2097152);
        unsigned short* Wt  = (unsigned short*)(ws + 2621440);
        float* Opart = ws;                                  // 4 x 1M floats
        unsigned short* Qb = (unsigned short*)(ws + 4194304);
        unsigned short* Kb = (unsigned short*)(ws + 4718592);
        unsigned short* Vt = (unsigned short*)(ws + 5242880);
        unsigned int*   ab32 = (unsigned int*)(ws + 5767168);
        float* Lpart = ws + 6291456;
        float* Linv  = ws + 6815744;

        prep_kernel<<<544, 256, 0, stream>>>(nf, Wq, Wk, NFb, Wt);
        proj_mfma<<<256, 256, 0, stream>>>(NFb, Wt, bq, bk, Qb, Kb);
        proj_v<<<128, 256, 0, stream>>>(msg, Wv, bv, Vf);
        abit_kernel<<<1024, 256, 0, stream>>>(adj, ab32);
        pack_vt<<<256, 256, 0, stream>>>(Vf, Vt, 0);
        sweep1_old<<<dim3(256, 4), 256, 0, stream>>>(Qb, Kb, ab32, Lpart);
        linv_kernel<<<128, 256, 0, stream>>>(Lpart, Linv, 16);
        sweep2_old<<<dim3(256, 4), 256, 0, stream>>>(Qb, Kb, Vt, ab32, Linv, Opart, amean);
        final_kernel<<<256, 256, 0, stream>>>(Opart, Wo, bo, routed, 4);
    }
}

// Round 17
// 202.977 us; speedup vs baseline: 1.8625x; 1.8625x over previous
//
#include <hip/hip_runtime.h>
#include <math.h>

#define NN 4096
#define HID 256
#define MD 32
#define NH 8
#define SCALE 0.17677669529663687f  // 1/sqrt(32)
#define QSCALE 0.25503164588f       // SCALE * log2(e)

typedef float f32x4 __attribute__((ext_vector_type(4)));
typedef short bf16x8 __attribute__((ext_vector_type(8)));
typedef _Float16 f16x8 __attribute__((ext_vector_type(8)));
typedef _Float16 f16x4 __attribute__((ext_vector_type(4)));
typedef _Float16 f16x2 __attribute__((ext_vector_type(2)));

#define EXP2(x) __builtin_amdgcn_exp2f(x)   // raw v_exp_f32 (D = 2^S0)

__device__ inline unsigned int bfr(float x) {             // f32 -> bf16 bits (RNE)
    unsigned int u = __float_as_uint(x);
    return (u + 0x7fffu + ((u >> 16) & 1u)) >> 16;
}
__device__ inline unsigned int pkbf(float a, float b) {
    return bfr(a) | (bfr(b) << 16);
}
__device__ inline unsigned int pkhf(float a, float b) {   // 2 x f16 (RNE)
    union { f16x2 h; unsigned int u; } z;
    z.h = (f16x2){(_Float16)a, (_Float16)b};
    return z.u;
}
__device__ inline unsigned int spread4(unsigned int x) {  // bit i -> bit 4i
    x = (x | (x << 12)) & 0x000F000Fu;
    x = (x | (x << 6))  & 0x03030303u;
    x = (x | (x << 3))  & 0x11111111u;
    return x;
}

// -------- prep: pack NF -> bf16, transpose Wq/Wk -> bf16 Wt[c][k] ---------
__global__ __launch_bounds__(256) void prep_kernel(
    const float* __restrict__ nf, const float* __restrict__ Wq,
    const float* __restrict__ Wk, unsigned short* __restrict__ NFb,
    unsigned short* __restrict__ Wt)
{
    __shared__ __align__(16) float lds[64 * 65];
    const int b = blockIdx.x, t = threadIdx.x;
    if (b < 512) {
        const float* src = nf + (size_t)b * 2048 + t * 8;
        float4 a = ((const float4*)src)[0];
        float4 c = ((const float4*)src)[1];
        uint4 o;
        o.x = pkbf(a.x, a.y); o.y = pkbf(a.z, a.w);
        o.z = pkbf(c.x, c.y); o.w = pkbf(c.z, c.w);
        *(uint4*)(NFb + (size_t)b * 2048 + t * 8) = o;
        return;
    }
    const int b2 = b - 512;
    const int mat = b2 >> 4, tile = b2 & 15;
    const int k0 = (tile >> 2) * 64, c0 = (tile & 3) * 64;
    const float* W = mat ? Wk : Wq;
    #pragma unroll
    for (int i = 0; i < 16; ++i) {
        int idx = i * 256 + t;
        int row = idx >> 4, c4 = idx & 15;
        float4 v = *(const float4*)(W + (size_t)(k0 + row) * 256 + c0 + c4 * 4);
        lds[row * 65 + c4 * 4 + 0] = v.x;
        lds[row * 65 + c4 * 4 + 1] = v.y;
        lds[row * 65 + c4 * 4 + 2] = v.z;
        lds[row * 65 + c4 * 4 + 3] = v.w;
    }
    __syncthreads();
    #pragma unroll
    for (int i = 0; i < 2; ++i) {
        int j = i * 256 + t;
        int c_loc = j >> 3, kq = j & 7;
        uint4 o;
        o.x = pkbf(lds[(kq * 8 + 0) * 65 + c_loc], lds[(kq * 8 + 1) * 65 + c_loc]);
        o.y = pkbf(lds[(kq * 8 + 2) * 65 + c_loc], lds[(kq * 8 + 3) * 65 + c_loc]);
        o.z = pkbf(lds[(kq * 8 + 4) * 65 + c_loc], lds[(kq * 8 + 5) * 65 + c_loc]);
        o.w = pkbf(lds[(kq * 8 + 6) * 65 + c_loc], lds[(kq * 8 + 7) * 65 + c_loc]);
        *(uint4*)(Wt + (size_t)mat * 65536 + (size_t)(c0 + c_loc) * 256 + k0 + kq * 8) = o;
    }
}

// -------- Q,K projection via MFMA (outT[c][n] = W^T . NF^T) ---------------
__global__ __launch_bounds__(256, 4) void proj_mfma(
    const unsigned short* __restrict__ NFb, const unsigned short* __restrict__ Wt,
    const float* __restrict__ bq, const float* __restrict__ bk,
    unsigned short* __restrict__ Qb, unsigned short* __restrict__ Kb)
{
    const int b = blockIdx.x;
    const int isK = b >> 7, nb = b & 127;
    const unsigned short* Wm = Wt + (size_t)isK * 65536;
    const float* bias = isK ? bk : bq;
    unsigned short* outp = isK ? Kb : Qb;
    const int t = threadIdx.x, w = t >> 6, l = t & 63;
    const int g = l >> 4, q = l & 15;
    const int n0 = nb * 32 + (w & 1) * 16;
    const int chalf = w >> 1;

    f32x4 acc[8];
    #pragma unroll
    for (int ct = 0; ct < 8; ++ct) acc[ct] = (f32x4){0.f, 0.f, 0.f, 0.f};

    #pragma unroll
    for (int kc = 0; kc < 8; ++kc) {
        bf16x8 bfrag = *(const bf16x8*)(NFb + (size_t)(n0 + q) * 256 + kc * 32 + g * 8);
        #pragma unroll
        for (int ct = 0; ct < 8; ++ct) {
            int c = (chalf * 8 + ct) * 16 + q;
            bf16x8 afrag = *(const bf16x8*)(Wm + (size_t)c * 256 + kc * 32 + g * 8);
            acc[ct] = __builtin_amdgcn_mfma_f32_16x16x32_bf16(afrag, bfrag, acc[ct], 0, 0, 0);
        }
    }
    const float sc = isK ? 1.0f : QSCALE;
    const int n = n0 + q;
    #pragma unroll
    for (int ct = 0; ct < 8; ++ct) {
        int c0 = (chalf * 8 + ct) * 16 + 4 * g;
        float4 bv = *(const float4*)(bias + c0);
        float v0 = (acc[ct][0] + bv.x) * sc;
        float v1 = (acc[ct][1] + bv.y) * sc;
        float v2 = (acc[ct][2] + bv.z) * sc;
        float v3 = (acc[ct][3] + bv.w) * sc;
        uint2 o;
        o.x = pkbf(v0, v1); o.y = pkbf(v2, v3);
        int h = c0 >> 5, d = c0 & 31;
        *(uint2*)(outp + ((size_t)h * NN + n) * 32 + d) = o;
    }
}

// -------- V projection (KD=32, tiny) --------------------------------------
__global__ __launch_bounds__(256) void proj_v(
    const float* __restrict__ msg, const float* __restrict__ Wv,
    const float* __restrict__ bv, float* __restrict__ Vo)
{
    __shared__ __align__(16) float in_lds[32 * 32];
    const int nb = blockIdx.x;
    const int t = threadIdx.x;
    ((float4*)in_lds)[t] = ((const float4*)(msg + (size_t)nb * 1024))[t];
    __syncthreads();
    float acc[32];
    #pragma unroll
    for (int r = 0; r < 32; ++r) acc[r] = 0.f;
    #pragma unroll 8
    for (int k = 0; k < 32; ++k) {
        float w = Wv[k * 256 + t];
        #pragma unroll
        for (int r = 0; r < 32; ++r) acc[r] += in_lds[r * 32 + k] * w;
    }
    const float bb = bv[t];
    #pragma unroll
    for (int r = 0; r < 32; ++r)
        Vo[(size_t)(nb * 32 + r) * 256 + t] = acc[r] + bb;
}

// ------------- adjacency bitmask: vectorized loads, OLD bit layout --------
__global__ __launch_bounds__(256) void abit_kernel(
    const int* __restrict__ adj, unsigned int* __restrict__ ab32)
{
    const int w = threadIdx.x >> 6, lane = threadIdx.x & 63;
    const int n = blockIdx.x * 4 + w;
    const int* base = adj + (size_t)n * NN;
    for (int it = 0; it < 16; ++it) {
        int4 v = *(const int4*)(base + it * 256 + lane * 4);
        unsigned long long b0 = __ballot(v.x != 0);
        unsigned long long b1 = __ballot(v.y != 0);
        unsigned long long b2 = __ballot(v.z != 0);
        unsigned long long b3 = __ballot(v.w != 0);
        if (lane < 8) {
            unsigned int sh = lane * 8;
            unsigned int B0 = (unsigned int)((b0 >> sh) & 0xffULL);
            unsigned int B1 = (unsigned int)((b1 >> sh) & 0xffULL);
            unsigned int B2 = (unsigned int)((b2 >> sh) & 0xffULL);
            unsigned int B3 = (unsigned int)((b3 >> sh) & 0xffULL);
            unsigned int wd = spread4(B0) | (spread4(B1) << 1)
                            | (spread4(B2) << 2) | (spread4(B3) << 3);
            ab32[(size_t)n * 128 + it * 8 + lane] = wd;
        }
    }
}

// -------- V f32 -> transposed Vt[h][d][m'] (permuted granules, r15) -------
__global__ __launch_bounds__(256) void pack_vt(
    const float* __restrict__ Vf, unsigned short* __restrict__ Vt, int usef16)
{
    __shared__ __align__(16) float lds[128 * 33];
    const int h = blockIdx.x >> 5, mt = blockIdx.x & 31;
    const int t = threadIdx.x;
    for (int k = 0; k < 4; ++k) {
        int flat = k * 256 + t;
        int row = flat >> 3, c4 = flat & 7;
        float4 v = *(const float4*)(Vf + (size_t)(mt * 128 + row) * 256 + h * 32 + c4 * 4);
        lds[row * 33 + c4 * 4 + 0] = v.x;
        lds[row * 33 + c4 * 4 + 1] = v.y;
        lds[row * 33 + c4 * 4 + 2] = v.z;
        lds[row * 33 + c4 * 4 + 3] = v.w;
    }
    __syncthreads();
    if (usef16) {
        #pragma unroll
        for (int it = 0; it < 2; ++it) {
            int jb = it * 256 + t;
            int d = jb >> 4, chs = jb & 15;
            int chunk = chs >> 2, seg = chs & 3;
            int mb = chunk * 32 + seg * 4;
            uint4 o;
            o.x = pkhf(lds[(mb + 0) * 33 + d],  lds[(mb + 1) * 33 + d]);
            o.y = pkhf(lds[(mb + 2) * 33 + d],  lds[(mb + 3) * 33 + d]);
            o.z = pkhf(lds[(mb + 16) * 33 + d], lds[(mb + 17) * 33 + d]);
            o.w = pkhf(lds[(mb + 18) * 33 + d], lds[(mb + 19) * 33 + d]);
            *(uint4*)(Vt + ((size_t)(h * 32 + d)) * NN + mt * 128 + chunk * 32 + seg * 8) = o;
        }
    } else {
        const int d = t >> 3, mq = t & 7;
        #pragma unroll
        for (int k = 0; k < 2; ++k) {
            int m0 = mq * 16 + k * 8;
            uint4 o;
            o.x = pkbf(lds[(m0 + 0) * 33 + d], lds[(m0 + 1) * 33 + d]);
            o.y = pkbf(lds[(m0 + 2) * 33 + d], lds[(m0 + 3) * 33 + d]);
            o.z = pkbf(lds[(m0 + 4) * 33 + d], lds[(m0 + 5) * 33 + d]);
            o.w = pkbf(lds[(m0 + 6) * 33 + d], lds[(m0 + 7) * 33 + d]);
            *(uint4*)(Vt + ((size_t)(h * 32 + d)) * NN + mt * 128 + m0) = o;
        }
    }
}

// ======================= STAGED SWEEPS ====================================
__global__ __launch_bounds__(256, 4) void sweep1s_kernel(
    const unsigned short* __restrict__ Qb, const unsigned short* __restrict__ Kb,
    const unsigned int* __restrict__ abit, float* __restrict__ Lpart)
{
    __shared__ __align__(16) char smem[32768];
    const int nquad = blockIdx.x, msg = blockIdx.y;
    const int t = threadIdx.x;
    const int w = t >> 6, l = t & 63;
    const int g = l >> 4, q = l & 15;
    const int n0 = nquad * 64 + w * 16;
    const int m0 = msg * 512;
    const int fq = (q >> 1) & 3;

    const char* gsrc[4];
    #pragma unroll
    for (int i = 0; i < 4; ++i) {
        int s = i * 256 + t;
        int tile = s >> 7;
        int r = (s >> 2) & 31;
        int gr = (s & 3) ^ ((r >> 1) & 3);
        gsrc[i] = (const char*)Kb + (((size_t)tile * NN + m0 + r) * 64 + gr * 16);
    }
    const unsigned int* abrow = abit + (size_t)(n0 + q) * 128 + msg * 16;

    bf16x8 qf[8];
    #pragma unroll
    for (int h = 0; h < 8; ++h)
        qf[h] = *(const bf16x8*)(Qb + (((size_t)h * NN + n0 + q) << 5) + g * 8);
    float lacc[8];
    #pragma unroll
    for (int h = 0; h < 8; ++h) lacc[h] = 0.f;

    #pragma unroll
    for (int i = 0; i < 4; ++i)
        __builtin_amdgcn_global_load_lds((const unsigned int*)gsrc[i],
            (unsigned int*)(smem + i * 4096 + w * 1024), 16, 0, 0);
    unsigned int wb = abrow[0];
    unsigned int wbn = 0;
    __syncthreads();

    for (int c = 0; c < 16; ++c) {
        const char* cur = smem + (c & 1) * 16384;
        if (c < 15) {
            wbn = abrow[c + 1];
            char* nxt = smem + ((c & 1) ^ 1) * 16384;
            #pragma unroll
            for (int i = 0; i < 4; ++i)
                __builtin_amdgcn_global_load_lds(
                    (const unsigned int*)(gsrc[i] + (size_t)(c + 1) * 2048),
                    (unsigned int*)(nxt + i * 4096 + w * 1024), 16, 0, 0);
        }
        #pragma unroll
        for (int h = 0; h < 8; ++h) {
            const int ko = h * 2048 + q * 64 + ((g ^ fq) << 4);
            bf16x8 ka0 = *(const bf16x8*)(cur + ko);
            bf16x8 ka1 = *(const bf16x8*)(cur + ko + 1024);
            f32x4 z = {0.f, 0.f, 0.f, 0.f};
            f32x4 s0 = __builtin_amdgcn_mfma_f32_16x16x32_bf16(ka0, qf[h], z, 0, 0, 0);
            f32x4 s1 = __builtin_amdgcn_mfma_f32_16x16x32_bf16(ka1, qf[h], z, 0, 0, 0);
            #pragma unroll
            for (int r = 0; r < 4; ++r) {
                float e0 = EXP2(s0[r]);
                float e1 = EXP2(s1[r]);
                lacc[h] += ((wb >> (4 * g + r)) & 1u) ? e0 : 0.f;
                lacc[h] += ((wb >> (16 + 4 * g + r)) & 1u) ? e1 : 0.f;
            }
        }
        __syncthreads();
        wb = wbn;
    }
    #pragma unroll
    for (int h = 0; h < 8; ++h) {
        float v = lacc[h];
        v += __shfl_xor(v, 16);
        v += __shfl_xor(v, 32);
        if (g == 0) Lpart[(size_t)msg * 32768 + h * NN + n0 + q] = v;
    }
}

// sweep2s: K staged (16KB x2), V direct from L2-resident permuted Vt.
// __launch_bounds__(256, 2): the ONLY bound proven to give the 128-VGPR cap
// (r11/r16: any "4" in slot 2 caps at 64 -> scratch spill catastrophe).
// Bound is a MINIMUM: with 32KB LDS + 128 VGPR the HW can still co-schedule
// up to 4 blocks/CU at runtime.
__global__ __launch_bounds__(256, 2) void sweep2s_kernel(
    const unsigned short* __restrict__ Qb, const unsigned short* __restrict__ Kb,
    const unsigned short* __restrict__ Vt, const unsigned int* __restrict__ abit,
    const float* __restrict__ Linv, float* __restrict__ Opart,
    float* __restrict__ amean)
{
    __shared__ __align__(16) char smem[32768];
    const int nquad = blockIdx.x, msg = blockIdx.y;
    const int t = threadIdx.x;
    const int w = t >> 6, l = t & 63;
    const int g = l >> 4, q = l & 15;
    const int n0 = nquad * 64 + w * 16;
    const int m0 = msg * 512;
    const int fq = (q >> 1) & 3;
    const _Float16* VtF = (const _Float16*)Vt;

    const char* gsrc[4];
    #pragma unroll
    for (int i = 0; i < 4; ++i) {
        int s = i * 256 + t;
        int tile = s >> 7;
        int r = (s >> 2) & 31;
        int gr = (s & 3) ^ ((r >> 1) & 3);
        gsrc[i] = (const char*)Kb + (((size_t)tile * NN + m0 + r) * 64 + gr * 16);
    }
    const unsigned int* abrow = abit + (size_t)(n0 + q) * 128 + msg * 16;

    bf16x8 qf[8];
    float rL[8];
    #pragma unroll
    for (int h = 0; h < 8; ++h) {
        qf[h] = *(const bf16x8*)(Qb + (((size_t)h * NN + n0 + q) << 5) + g * 8);
        rL[h] = Linv[h * NN + n0 + q];
    }
    f32x4 o[8][2];
    #pragma unroll
    for (int h = 0; h < 8; ++h) {
        o[h][0] = (f32x4){0.f, 0.f, 0.f, 0.f};
        o[h][1] = (f32x4){0.f, 0.f, 0.f, 0.f};
    }

    #pragma unroll
    for (int i = 0; i < 4; ++i)
        __builtin_amdgcn_global_load_lds((const unsigned int*)gsrc[i],
            (unsigned int*)(smem + i * 4096 + w * 1024), 16, 0, 0);
    unsigned int wb = abrow[0];
    unsigned int wbn = 0;
    __syncthreads();

    for (int c = 0; c < 16; ++c) {
        const char* cur = smem + (c & 1) * 16384;
        if (c < 15) {
            wbn = abrow[c + 1];
            char* nxt = smem + ((c & 1) ^ 1) * 16384;
            #pragma unroll
            for (int i = 0; i < 4; ++i)
                __builtin_amdgcn_global_load_lds(
                    (const unsigned int*)(gsrc[i] + (size_t)(c + 1) * 2048),
                    (unsigned int*)(nxt + i * 4096 + w * 1024), 16, 0, 0);
        }
        const int mb = m0 + c * 32;
        float am[8];
        #pragma unroll
        for (int r = 0; r < 8; ++r) am[r] = 0.f;

        #pragma unroll
        for (int h = 0; h < 8; ++h) {
            const int ko = h * 2048 + q * 64 + ((g ^ fq) << 4);
            bf16x8 ka0 = *(const bf16x8*)(cur + ko);
            bf16x8 ka1 = *(const bf16x8*)(cur + ko + 1024);
            // V direct from global (permuted Vt, linear address, no swizzle)
            const _Float16* vg = VtF + ((size_t)(h * 32 + q)) * NN + mb + g * 8;
            f16x8 lo8 = *(const f16x8*)(vg);                   // d = q
            f16x8 hi8 = *(const f16x8*)(vg + (size_t)16 * NN); // d = 16+q
            f16x4 va00 = __builtin_shufflevector(lo8, lo8, 0, 1, 2, 3);
            f16x4 va10 = __builtin_shufflevector(lo8, lo8, 4, 5, 6, 7);
            f16x4 va01 = __builtin_shufflevector(hi8, hi8, 0, 1, 2, 3);
            f16x4 va11 = __builtin_shufflevector(hi8, hi8, 4, 5, 6, 7);
            f32x4 z = {0.f, 0.f, 0.f, 0.f};
            f32x4 s0 = __builtin_amdgcn_mfma_f32_16x16x32_bf16(ka0, qf[h], z, 0, 0, 0);
            f32x4 s1 = __builtin_amdgcn_mfma_f32_16x16x32_bf16(ka1, qf[h], z, 0, 0, 0);
            float pn[8];
            #pragma unroll
            for (int r = 0; r < 4; ++r) {
                float e0 = EXP2(s0[r]) * rL[h];
                float e1 = EXP2(s1[r]) * rL[h];
                pn[r]     = ((wb >> (4 * g + r)) & 1u) ? e0 : 0.f;
                pn[4 + r] = ((wb >> (16 + 4 * g + r)) & 1u) ? e1 : 0.f;
                am[r] += pn[r];
                am[4 + r] += pn[4 + r];
            }
            union { unsigned int u[2]; f16x4 v; } pA, pB;
            pA.u[0] = pkhf(pn[0], pn[1]); pA.u[1] = pkhf(pn[2], pn[3]);
            pB.u[0] = pkhf(pn[4], pn[5]); pB.u[1] = pkhf(pn[6], pn[7]);
            o[h][0] = __builtin_amdgcn_mfma_f32_16x16x16f16(va00, pA.v, o[h][0], 0, 0, 0);
            o[h][1] = __builtin_amdgcn_mfma_f32_16x16x16f16(va01, pA.v, o[h][1], 0, 0, 0);
            o[h][0] = __builtin_amdgcn_mfma_f32_16x16x16f16(va10, pB.v, o[h][0], 0, 0, 0);
            o[h][1] = __builtin_amdgcn_mfma_f32_16x16x16f16(va11, pB.v, o[h][1], 0, 0, 0);
        }
        float4 a0, a1;
        a0.x = am[0] * 0.125f; a0.y = am[1] * 0.125f;
        a0.z = am[2] * 0.125f; a0.w = am[3] * 0.125f;
        a1.x = am[4] * 0.125f; a1.y = am[5] * 0.125f;
        a1.z = am[6] * 0.125f; a1.w = am[7] * 0.125f;
        *(float4*)(amean + (size_t)(n0 + q) * NN + mb + 4 * g) = a0;
        *(float4*)(amean + (size_t)(n0 + q) * NN + mb + 16 + 4 * g) = a1;
        __syncthreads();
        wb = wbn;
    }

    float* op = Opart + ((size_t)msg * NN + n0 + q) * 256;
    #pragma unroll
    for (int h = 0; h < 8; ++h) {
        *(f32x4*)(op + h * 32 + 4 * g) = o[h][0];
        *(f32x4*)(op + h * 32 + 16 + 4 * g) = o[h][1];
    }
}

// ======================= OLD SWEEPS (path B fallback) =====================
__global__ __launch_bounds__(256, 4) void sweep1_old(
    const unsigned short* __restrict__ Qb, const unsigned short* __restrict__ Kb,
    const unsigned int* __restrict__ abit, float* __restrict__ Lpart)
{
    const int ntile = blockIdx.x, msg = blockIdx.y;
    const int t = threadIdx.x;
    const int w = t >> 6, l = t & 63;
    const int g = l >> 4, q = l & 15;
    const int ms = msg * 4 + w;
    const int n0 = ntile * 16;
    const int mbase = ms * 256;
    bf16x8 qf[8];
    #pragma unroll
    for (int h = 0; h < 8; ++h)
        qf[h] = *(const bf16x8*)(Qb + (((size_t)h * NN + n0 + q) << 5) + g * 8);
    float lacc[8];
    #pragma unroll
    for (int h = 0; h < 8; ++h) lacc[h] = 0.f;
    for (int ch = 0; ch < 8; ++ch) {
        const int mb = mbase + ch * 32;
        const unsigned int wbits = abit[(size_t)(n0 + q) * 128 + (mb >> 5)];
        #pragma unroll
        for (int h = 0; h < 8; ++h) {
            bf16x8 ka0 = *(const bf16x8*)(Kb + (((size_t)h * NN + mb + q) << 5) + g * 8);
            bf16x8 ka1 = *(const bf16x8*)(Kb + (((size_t)h * NN + mb + 16 + q) << 5) + g * 8);
            f32x4 z = {0.f, 0.f, 0.f, 0.f};
            f32x4 s0 = __builtin_amdgcn_mfma_f32_16x16x32_bf16(ka0, qf[h], z, 0, 0, 0);
            f32x4 s1 = __builtin_amdgcn_mfma_f32_16x16x32_bf16(ka1, qf[h], z, 0, 0, 0);
            #pragma unroll
            for (int r = 0; r < 4; ++r) {
                float e0 = EXP2(s0[r]);
                float e1 = EXP2(s1[r]);
                lacc[h] += ((wbits >> (4 * g + r)) & 1u) ? e0 : 0.f;
                lacc[h] += ((wbits >> (16 + 4 * g + r)) & 1u) ? e1 : 0.f;
            }
        }
    }
    #pragma unroll
    for (int h = 0; h < 8; ++h) {
        float v = lacc[h];
        v += __shfl_xor(v, 16);
        v += __shfl_xor(v, 32);
        if (g == 0) Lpart[(size_t)ms * 32768 + h * NN + n0 + q] = v;
    }
}

__global__ __launch_bounds__(256, 2) void sweep2_old(
    const unsigned short* __restrict__ Qb, const unsigned short* __restrict__ Kb,
    const unsigned short* __restrict__ Vt, const unsigned int* __restrict__ abit,
    const float* __restrict__ Linv, float* __restrict__ Opart,
    float* __restrict__ amean)
{
    __shared__ __align__(16) float Ow[2 * 16 * 260];
    const int ntile = blockIdx.x, msg = blockIdx.y;
    const int t = threadIdx.x;
    const int w = t >> 6, l = t & 63;
    const int g = l >> 4, q = l & 15;
    const int ms = msg * 4 + w;
    const int n0 = ntile * 16;
    const int mbase = ms * 256;
    const int baddr = (q + (g & 1) * 32) << 2;
    const bool hi = (g >= 2);
    bf16x8 qf[8];
    float rL[8];
    #pragma unroll
    for (int h = 0; h < 8; ++h) {
        qf[h] = *(const bf16x8*)(Qb + (((size_t)h * NN + n0 + q) << 5) + g * 8);
        rL[h] = Linv[h * NN + n0 + q];
    }
    f32x4 o[8][2];
    #pragma unroll
    for (int h = 0; h < 8; ++h) {
        o[h][0] = (f32x4){0.f, 0.f, 0.f, 0.f};
        o[h][1] = (f32x4){0.f, 0.f, 0.f, 0.f};
    }
    for (int ch = 0; ch < 8; ++ch) {
        const int mb = mbase + ch * 32;
        const unsigned int wbits = abit[(size_t)(n0 + q) * 128 + (mb >> 5)];
        float am[8];
        #pragma unroll
        for (int r = 0; r < 8; ++r) am[r] = 0.f;
        #pragma unroll
        for (int h = 0; h < 8; ++h) {
            bf16x8 ka0 = *(const bf16x8*)(Kb + (((size_t)h * NN + mb + q) << 5) + g * 8);
            bf16x8 ka1 = *(const bf16x8*)(Kb + (((size_t)h * NN + mb + 16 + q) << 5) + g * 8);
            f32x4 z = {0.f, 0.f, 0.f, 0.f};
            f32x4 s0 = __builtin_amdgcn_mfma_f32_16x16x32_bf16(ka0, qf[h], z, 0, 0, 0);
            f32x4 s1 = __builtin_amdgcn_mfma_f32_16x16x32_bf16(ka1, qf[h], z, 0, 0, 0);
            float pn[8];
            #pragma unroll
            for (int r = 0; r < 4; ++r) {
                float e0 = EXP2(s0[r]) * rL[h];
                float e1 = EXP2(s1[r]) * rL[h];
                pn[r]     = ((wbits >> (4 * g + r)) & 1u) ? e0 : 0.f;
                pn[4 + r] = ((wbits >> (16 + 4 * g + r)) & 1u) ? e1 : 0.f;
                am[r] += pn[r];
                am[4 + r] += pn[4 + r];
            }
            unsigned int pk0 = pkbf(pn[0], pn[1]);
            unsigned int pk1 = pkbf(pn[2], pn[3]);
            unsigned int pk2 = pkbf(pn[4], pn[5]);
            unsigned int pk3 = pkbf(pn[6], pn[7]);
            int r0lo = __builtin_amdgcn_ds_bpermute(baddr,      (int)pk0);
            int r0hi = __builtin_amdgcn_ds_bpermute(baddr,      (int)pk2);
            int r1lo = __builtin_amdgcn_ds_bpermute(baddr,      (int)pk1);
            int r1hi = __builtin_amdgcn_ds_bpermute(baddr,      (int)pk3);
            int r2lo = __builtin_amdgcn_ds_bpermute(baddr + 64, (int)pk0);
            int r2hi = __builtin_amdgcn_ds_bpermute(baddr + 64, (int)pk2);
            int r3lo = __builtin_amdgcn_ds_bpermute(baddr + 64, (int)pk1);
            int r3hi = __builtin_amdgcn_ds_bpermute(baddr + 64, (int)pk3);
            union { unsigned int u[4]; bf16x8 v; } pu;
            pu.u[0] = (unsigned int)(hi ? r0hi : r0lo);
            pu.u[1] = (unsigned int)(hi ? r1hi : r1lo);
            pu.u[2] = (unsigned int)(hi ? r2hi : r2lo);
            pu.u[3] = (unsigned int)(hi ? r3hi : r3lo);
            bf16x8 va0 = *(const bf16x8*)(Vt + ((size_t)(h * 32 + q)) * NN + mb + g * 8);
            bf16x8 va1 = *(const bf16x8*)(Vt + ((size_t)(h * 32 + 16 + q)) * NN + mb + g * 8);
            o[h][0] = __builtin_amdgcn_mfma_f32_16x16x32_bf16(va0, pu.v, o[h][0], 0, 0, 0);
            o[h][1] = __builtin_amdgcn_mfma_f32_16x16x32_bf16(va1, pu.v, o[h][1], 0, 0, 0);
        }
        float4 a0, a1;
        a0.x = am[0] * 0.125f; a0.y = am[1] * 0.125f;
        a0.z = am[2] * 0.125f; a0.w = am[3] * 0.125f;
        a1.x = am[4] * 0.125f; a1.y = am[5] * 0.125f;
        a1.z = am[6] * 0.125f; a1.w = am[7] * 0.125f;
        *(float4*)(amean + (size_t)(n0 + q) * NN + mb + 4 * g) = a0;
        *(float4*)(amean + (size_t)(n0 + q) * NN + mb + 16 + 4 * g) = a1;
    }
    if (w < 2) {
        #pragma unroll
        for (int h = 0; h < 8; ++h)
            #pragma unroll
            for (int dt = 0; dt < 2; ++dt)
                *(f32x4*)&Ow[w * 4160 + q * 260 + h * 32 + dt * 16 + 4 * g] = o[h][dt];
    }
    __syncthreads();
    if (w >= 2) {
        #pragma unroll
        for (int h = 0; h < 8; ++h)
            #pragma unroll
            for (int dt = 0; dt < 2; ++dt) {
                f32x4* p = (f32x4*)&Ow[(w - 2) * 4160 + q * 260 + h * 32 + dt * 16 + 4 * g];
                *p = *p + o[h][dt];
            }
    }
    __syncthreads();
    for (int i = t; i < 4096; i += 256) {
        int n = i >> 8, c2 = i & 255;
        float v = Ow[n * 260 + c2] + Ow[4160 + n * 260 + c2];
        Opart[((size_t)msg * NN + n0 + n) * 256 + c2] = v;
    }
}

// ---------------- Linv ----------------------------------------------------
__global__ __launch_bounds__(256) void linv_kernel(
    const float* __restrict__ Lpart, float* __restrict__ Linv, int nms)
{
    int i = blockIdx.x * 256 + threadIdx.x;
    float s = 0.f;
    for (int ms = 0; ms < nms; ++ms) s += Lpart[(size_t)ms * 32768 + i];
    Linv[i] = 1.0f / s;
}

// -------- finalize: routed = (sum_ms Opart) @ Wo + bo ---------------------
__global__ __launch_bounds__(256) void final_kernel(
    const float* __restrict__ Opart, const float* __restrict__ Wo,
    const float* __restrict__ bo, float* __restrict__ routed, int nms)
{
    __shared__ __align__(16) float Osum[16 * 260];
    __shared__ __align__(16) float WoT[32 * 260];
    const int nb = blockIdx.x, t = threadIdx.x;
    for (int i4 = t; i4 < 2048; i4 += 256) {
        int k = i4 >> 3, j4b = i4 & 7;
        float4 v = *(const float4*)(Wo + k * 32 + j4b * 4);
        WoT[(j4b * 4 + 0) * 260 + k] = v.x;
        WoT[(j4b * 4 + 1) * 260 + k] = v.y;
        WoT[(j4b * 4 + 2) * 260 + k] = v.z;
        WoT[(j4b * 4 + 3) * 260 + k] = v.w;
    }
    for (int i = t; i < 4096; i += 256) {
        int r = i >> 8, c = i & 255;
        const float* ap = Opart + ((size_t)(nb * 16 + r)) * 256 + c;
        float s = 0.f;
        for (int ms = 0; ms < nms; ++ms) s += ap[(size_t)ms * 1048576];
        Osum[r * 260 + c] = s;
    }
    __syncthreads();
    const int rh = t >> 5, j = t & 31;
    const float bj = bo[j];
    #pragma unroll
    for (int rr = 0; rr < 2; ++rr) {
        int r = rh * 2 + rr;
        float a0 = 0.f, a1 = 0.f;
        #pragma unroll
        for (int i4 = 0; i4 < 64; i4 += 2) {
            float4 ov = *(const float4*)&Osum[r * 260 + i4 * 4];
            float4 wv = *(const float4*)&WoT[j * 260 + i4 * 4];
            a0 += ov.x * wv.x + ov.y * wv.y + ov.z * wv.z + ov.w * wv.w;
            float4 ov2 = *(const float4*)&Osum[r * 260 + i4 * 4 + 4];
            float4 wv2 = *(const float4*)&WoT[j * 260 + i4 * 4 + 4];
            a1 += ov2.x * wv2.x + ov2.y * wv2.y + ov2.z * wv2.z + ov2.w * wv2.w;
        }
        routed[(size_t)(nb * 16 + r) * 32 + j] = a0 + a1 + bj;
    }
}

extern "C" void kernel_launch(void* const* d_in, const int* in_sizes, int n_in,
                              void* d_out, int out_size, void* d_ws, size_t ws_size,
                              hipStream_t stream) {
    const float* nf  = (const float*)d_in[0];
    const float* msg = (const float*)d_in[1];
    const int*   adj = (const int*)d_in[2];
    const float* Wq  = (const float*)d_in[3];
    const float* bq  = (const float*)d_in[4];
    const float* Wk  = (const float*)d_in[5];
    const float* bk  = (const float*)d_in[6];
    const float* Wv  = (const float*)d_in[7];
    const float* bv  = (const float*)d_in[8];
    const float* Wo  = (const float*)d_in[9];
    const float* bo  = (const float*)d_in[10];

    float* routed = (float*)d_out;
    float* amean  = (float*)d_out + (size_t)NN * MD;
    float* ws = (float*)d_ws;

    const bool bigws = (ws_size >= 43122688ull);

    if (bigws) {
        float* Vf = ws;                                     // dead before sweep2s
        unsigned short* NFb = (unsigned short*)(ws + 2097152);
        unsigned short* Wt  = (unsigned short*)(ws + 2621440);
        float* Opart = ws;                                  // 8 x 1M floats
        unsigned short* Qb = (unsigned short*)(ws + 8388608);
        unsigned short* Kb = (unsigned short*)(ws + 8912896);
        unsigned short* Vt = (unsigned short*)(ws + 9437184);
        unsigned int*   ab32 = (unsigned int*)(ws + 9961472);
        float* Lpart = ws + 10485760;
        float* Linv  = ws + 10747904;

        prep_kernel<<<544, 256, 0, stream>>>(nf, Wq, Wk, NFb, Wt);
        proj_mfma<<<256, 256, 0, stream>>>(NFb, Wt, bq, bk, Qb, Kb);
        proj_v<<<128, 256, 0, stream>>>(msg, Wv, bv, Vf);
        abit_kernel<<<1024, 256, 0, stream>>>(adj, ab32);
        pack_vt<<<256, 256, 0, stream>>>(Vf, Vt, 1);
        sweep1s_kernel<<<dim3(64, 8), 256, 0, stream>>>(Qb, Kb, ab32, Lpart);
        linv_kernel<<<128, 256, 0, stream>>>(Lpart, Linv, 8);
        sweep2s_kernel<<<dim3(64, 8), 256, 0, stream>>>(Qb, Kb, Vt, ab32, Linv, Opart, amean);
        final_kernel<<<256, 256, 0, stream>>>(Opart, Wo, bo, routed, 8);
    } else {
        float* Vf = ws;
        unsigned short* NFb = (unsigned short*)(ws + 2097152);
        unsigned short* Wt  = (unsigned short*)(ws + 2621440);
        float* Opart = ws;                                  // 4 x 1M floats
        unsigned short* Qb = (unsigned short*)(ws + 4194304);
        unsigned short* Kb = (unsigned short*)(ws + 4718592);
        unsigned short* Vt = (unsigned short*)(ws + 5242880);
        unsigned int*   ab32 = (unsigned int*)(ws + 5767168);
        float* Lpart = ws + 6291456;
        float* Linv  = ws + 6815744;

        prep_kernel<<<544, 256, 0, stream>>>(nf, Wq, Wk, NFb, Wt);
        proj_mfma<<<256, 256, 0, stream>>>(NFb, Wt, bq, bk, Qb, Kb);
        proj_v<<<128, 256, 0, stream>>>(msg, Wv, bv, Vf);
        abit_kernel<<<1024, 256, 0, stream>>>(adj, ab32);
        pack_vt<<<256, 256, 0, stream>>>(Vf, Vt, 0);
        sweep1_old<<<dim3(256, 4), 256, 0, stream>>>(Qb, Kb, ab32, Lpart);
        linv_kernel<<<128, 256, 0, stream>>>(Lpart, Linv, 16);
        sweep2_old<<<dim3(256, 4), 256, 0, stream>>>(Qb, Kb, Vt, ab32, Linv, Opart, amean);
        final_kernel<<<256, 256, 0, stream>>>(Opart, Wo, bo, routed, 4);
    }
}

// Round 18
// 169.821 us; speedup vs baseline: 2.2262x; 1.1952x over previous
//
#include <hip/hip_runtime.h>
#include <math.h>

#define NN 4096
#define HID 256
#define MD 32
#define NH 8
#define SCALE 0.17677669529663687f  // 1/sqrt(32)
#define QSCALE 0.25503164588f       // SCALE * log2(e)

typedef float f32x4 __attribute__((ext_vector_type(4)));
typedef short bf16x8 __attribute__((ext_vector_type(8)));
typedef _Float16 f16x8 __attribute__((ext_vector_type(8)));
typedef _Float16 f16x4 __attribute__((ext_vector_type(4)));
typedef _Float16 f16x2 __attribute__((ext_vector_type(2)));

#define EXP2(x) __builtin_amdgcn_exp2f(x)   // raw v_exp_f32 (D = 2^S0)

__device__ inline unsigned int bfr(float x) {             // f32 -> bf16 bits (RNE)
    unsigned int u = __float_as_uint(x);
    return (u + 0x7fffu + ((u >> 16) & 1u)) >> 16;
}
__device__ inline unsigned int pkbf(float a, float b) {
    return bfr(a) | (bfr(b) << 16);
}
__device__ inline unsigned int pkhf(float a, float b) {   // 2 x f16 (RNE)
    union { f16x2 h; unsigned int u; } z;
    z.h = (f16x2){(_Float16)a, (_Float16)b};
    return z.u;
}
__device__ inline unsigned int spread4(unsigned int x) {  // bit i -> bit 4i
    x = (x | (x << 12)) & 0x000F000Fu;
    x = (x | (x << 6))  & 0x03030303u;
    x = (x | (x << 3))  & 0x11111111u;
    return x;
}

// -------- prep: pack NF -> bf16, transpose Wq/Wk -> bf16 Wt[c][k] ---------
__global__ __launch_bounds__(256) void prep_kernel(
    const float* __restrict__ nf, const float* __restrict__ Wq,
    const float* __restrict__ Wk, unsigned short* __restrict__ NFb,
    unsigned short* __restrict__ Wt)
{
    __shared__ __align__(16) float lds[64 * 65];
    const int b = blockIdx.x, t = threadIdx.x;
    if (b < 512) {
        const float* src = nf + (size_t)b * 2048 + t * 8;
        float4 a = ((const float4*)src)[0];
        float4 c = ((const float4*)src)[1];
        uint4 o;
        o.x = pkbf(a.x, a.y); o.y = pkbf(a.z, a.w);
        o.z = pkbf(c.x, c.y); o.w = pkbf(c.z, c.w);
        *(uint4*)(NFb + (size_t)b * 2048 + t * 8) = o;
        return;
    }
    const int b2 = b - 512;
    const int mat = b2 >> 4, tile = b2 & 15;
    const int k0 = (tile >> 2) * 64, c0 = (tile & 3) * 64;
    const float* W = mat ? Wk : Wq;
    #pragma unroll
    for (int i = 0; i < 16; ++i) {
        int idx = i * 256 + t;
        int row = idx >> 4, c4 = idx & 15;
        float4 v = *(const float4*)(W + (size_t)(k0 + row) * 256 + c0 + c4 * 4);
        lds[row * 65 + c4 * 4 + 0] = v.x;
        lds[row * 65 + c4 * 4 + 1] = v.y;
        lds[row * 65 + c4 * 4 + 2] = v.z;
        lds[row * 65 + c4 * 4 + 3] = v.w;
    }
    __syncthreads();
    #pragma unroll
    for (int i = 0; i < 2; ++i) {
        int j = i * 256 + t;
        int c_loc = j >> 3, kq = j & 7;
        uint4 o;
        o.x = pkbf(lds[(kq * 8 + 0) * 65 + c_loc], lds[(kq * 8 + 1) * 65 + c_loc]);
        o.y = pkbf(lds[(kq * 8 + 2) * 65 + c_loc], lds[(kq * 8 + 3) * 65 + c_loc]);
        o.z = pkbf(lds[(kq * 8 + 4) * 65 + c_loc], lds[(kq * 8 + 5) * 65 + c_loc]);
        o.w = pkbf(lds[(kq * 8 + 6) * 65 + c_loc], lds[(kq * 8 + 7) * 65 + c_loc]);
        *(uint4*)(Wt + (size_t)mat * 65536 + (size_t)(c0 + c_loc) * 256 + k0 + kq * 8) = o;
    }
}

// -------- Q,K projection via MFMA (outT[c][n] = W^T . NF^T) ---------------
__global__ __launch_bounds__(256, 4) void proj_mfma(
    const unsigned short* __restrict__ NFb, const unsigned short* __restrict__ Wt,
    const float* __restrict__ bq, const float* __restrict__ bk,
    unsigned short* __restrict__ Qb, unsigned short* __restrict__ Kb)
{
    const int b = blockIdx.x;
    const int isK = b >> 7, nb = b & 127;
    const unsigned short* Wm = Wt + (size_t)isK * 65536;
    const float* bias = isK ? bk : bq;
    unsigned short* outp = isK ? Kb : Qb;
    const int t = threadIdx.x, w = t >> 6, l = t & 63;
    const int g = l >> 4, q = l & 15;
    const int n0 = nb * 32 + (w & 1) * 16;
    const int chalf = w >> 1;

    f32x4 acc[8];
    #pragma unroll
    for (int ct = 0; ct < 8; ++ct) acc[ct] = (f32x4){0.f, 0.f, 0.f, 0.f};

    #pragma unroll
    for (int kc = 0; kc < 8; ++kc) {
        bf16x8 bfrag = *(const bf16x8*)(NFb + (size_t)(n0 + q) * 256 + kc * 32 + g * 8);
        #pragma unroll
        for (int ct = 0; ct < 8; ++ct) {
            int c = (chalf * 8 + ct) * 16 + q;
            bf16x8 afrag = *(const bf16x8*)(Wm + (size_t)c * 256 + kc * 32 + g * 8);
            acc[ct] = __builtin_amdgcn_mfma_f32_16x16x32_bf16(afrag, bfrag, acc[ct], 0, 0, 0);
        }
    }
    const float sc = isK ? 1.0f : QSCALE;
    const int n = n0 + q;
    #pragma unroll
    for (int ct = 0; ct < 8; ++ct) {
        int c0 = (chalf * 8 + ct) * 16 + 4 * g;
        float4 bv = *(const float4*)(bias + c0);
        float v0 = (acc[ct][0] + bv.x) * sc;
        float v1 = (acc[ct][1] + bv.y) * sc;
        float v2 = (acc[ct][2] + bv.z) * sc;
        float v3 = (acc[ct][3] + bv.w) * sc;
        uint2 o;
        o.x = pkbf(v0, v1); o.y = pkbf(v2, v3);
        int h = c0 >> 5, d = c0 & 31;
        *(uint2*)(outp + ((size_t)h * NN + n) * 32 + d) = o;
    }
}

// -------- V projection (KD=32, tiny) --------------------------------------
__global__ __launch_bounds__(256) void proj_v(
    const float* __restrict__ msg, const float* __restrict__ Wv,
    const float* __restrict__ bv, float* __restrict__ Vo)
{
    __shared__ __align__(16) float in_lds[32 * 32];
    const int nb = blockIdx.x;
    const int t = threadIdx.x;
    ((float4*)in_lds)[t] = ((const float4*)(msg + (size_t)nb * 1024))[t];
    __syncthreads();
    float acc[32];
    #pragma unroll
    for (int r = 0; r < 32; ++r) acc[r] = 0.f;
    #pragma unroll 8
    for (int k = 0; k < 32; ++k) {
        float w = Wv[k * 256 + t];
        #pragma unroll
        for (int r = 0; r < 32; ++r) acc[r] += in_lds[r * 32 + k] * w;
    }
    const float bb = bv[t];
    #pragma unroll
    for (int r = 0; r < 32; ++r)
        Vo[(size_t)(nb * 32 + r) * 256 + t] = acc[r] + bb;
}

// ------------- adjacency bitmask: vectorized loads, OLD bit layout --------
__global__ __launch_bounds__(256) void abit_kernel(
    const int* __restrict__ adj, unsigned int* __restrict__ ab32)
{
    const int w = threadIdx.x >> 6, lane = threadIdx.x & 63;
    const int n = blockIdx.x * 4 + w;
    const int* base = adj + (size_t)n * NN;
    for (int it = 0; it < 16; ++it) {
        int4 v = *(const int4*)(base + it * 256 + lane * 4);
        unsigned long long b0 = __ballot(v.x != 0);
        unsigned long long b1 = __ballot(v.y != 0);
        unsigned long long b2 = __ballot(v.z != 0);
        unsigned long long b3 = __ballot(v.w != 0);
        if (lane < 8) {
            unsigned int sh = lane * 8;
            unsigned int B0 = (unsigned int)((b0 >> sh) & 0xffULL);
            unsigned int B1 = (unsigned int)((b1 >> sh) & 0xffULL);
            unsigned int B2 = (unsigned int)((b2 >> sh) & 0xffULL);
            unsigned int B3 = (unsigned int)((b3 >> sh) & 0xffULL);
            unsigned int wd = spread4(B0) | (spread4(B1) << 1)
                            | (spread4(B2) << 2) | (spread4(B3) << 3);
            ab32[(size_t)n * 128 + it * 8 + lane] = wd;
        }
    }
}

// -------- V f32 -> transposed Vt[h][d][m'] (permuted granules) ------------
__global__ __launch_bounds__(256) void pack_vt(
    const float* __restrict__ Vf, unsigned short* __restrict__ Vt, int usef16)
{
    __shared__ __align__(16) float lds[128 * 33];
    const int h = blockIdx.x >> 5, mt = blockIdx.x & 31;
    const int t = threadIdx.x;
    for (int k = 0; k < 4; ++k) {
        int flat = k * 256 + t;
        int row = flat >> 3, c4 = flat & 7;
        float4 v = *(const float4*)(Vf + (size_t)(mt * 128 + row) * 256 + h * 32 + c4 * 4);
        lds[row * 33 + c4 * 4 + 0] = v.x;
        lds[row * 33 + c4 * 4 + 1] = v.y;
        lds[row * 33 + c4 * 4 + 2] = v.z;
        lds[row * 33 + c4 * 4 + 3] = v.w;
    }
    __syncthreads();
    if (usef16) {
        #pragma unroll
        for (int it = 0; it < 2; ++it) {
            int jb = it * 256 + t;
            int d = jb >> 4, chs = jb & 15;
            int chunk = chs >> 2, seg = chs & 3;
            int mb = chunk * 32 + seg * 4;
            uint4 o;
            o.x = pkhf(lds[(mb + 0) * 33 + d],  lds[(mb + 1) * 33 + d]);
            o.y = pkhf(lds[(mb + 2) * 33 + d],  lds[(mb + 3) * 33 + d]);
            o.z = pkhf(lds[(mb + 16) * 33 + d], lds[(mb + 17) * 33 + d]);
            o.w = pkhf(lds[(mb + 18) * 33 + d], lds[(mb + 19) * 33 + d]);
            *(uint4*)(Vt + ((size_t)(h * 32 + d)) * NN + mt * 128 + chunk * 32 + seg * 8) = o;
        }
    } else {
        const int d = t >> 3, mq = t & 7;
        #pragma unroll
        for (int k = 0; k < 2; ++k) {
            int m0 = mq * 16 + k * 8;
            uint4 o;
            o.x = pkbf(lds[(m0 + 0) * 33 + d], lds[(m0 + 1) * 33 + d]);
            o.y = pkbf(lds[(m0 + 2) * 33 + d], lds[(m0 + 3) * 33 + d]);
            o.z = pkbf(lds[(m0 + 4) * 33 + d], lds[(m0 + 5) * 33 + d]);
            o.w = pkbf(lds[(m0 + 6) * 33 + d], lds[(m0 + 7) * 33 + d]);
            *(uint4*)(Vt + ((size_t)(h * 32 + d)) * NN + mt * 128 + m0) = o;
        }
    }
}

// ======================= STAGED SWEEPS (r15-proven best) ==================
__global__ __launch_bounds__(256, 4) void sweep1s_kernel(
    const unsigned short* __restrict__ Qb, const unsigned short* __restrict__ Kb,
    const unsigned int* __restrict__ abit, float* __restrict__ Lpart)
{
    __shared__ __align__(16) char smem[32768];
    const int nquad = blockIdx.x, msg = blockIdx.y;
    const int t = threadIdx.x;
    const int w = t >> 6, l = t & 63;
    const int g = l >> 4, q = l & 15;
    const int n0 = nquad * 64 + w * 16;
    const int m0 = msg * 512;
    const int fq = (q >> 1) & 3;

    const char* gsrc[4];
    #pragma unroll
    for (int i = 0; i < 4; ++i) {
        int s = i * 256 + t;
        int tile = s >> 7;
        int r = (s >> 2) & 31;
        int gr = (s & 3) ^ ((r >> 1) & 3);
        gsrc[i] = (const char*)Kb + (((size_t)tile * NN + m0 + r) * 64 + gr * 16);
    }
    const unsigned int* abrow = abit + (size_t)(n0 + q) * 128 + msg * 16;

    bf16x8 qf[8];
    #pragma unroll
    for (int h = 0; h < 8; ++h)
        qf[h] = *(const bf16x8*)(Qb + (((size_t)h * NN + n0 + q) << 5) + g * 8);
    float lacc[8];
    #pragma unroll
    for (int h = 0; h < 8; ++h) lacc[h] = 0.f;

    #pragma unroll
    for (int i = 0; i < 4; ++i)
        __builtin_amdgcn_global_load_lds((const unsigned int*)gsrc[i],
            (unsigned int*)(smem + i * 4096 + w * 1024), 16, 0, 0);
    unsigned int wb = abrow[0];
    unsigned int wbn = 0;
    __syncthreads();

    for (int c = 0; c < 16; ++c) {
        const char* cur = smem + (c & 1) * 16384;
        if (c < 15) {
            wbn = abrow[c + 1];
            char* nxt = smem + ((c & 1) ^ 1) * 16384;
            #pragma unroll
            for (int i = 0; i < 4; ++i)
                __builtin_amdgcn_global_load_lds(
                    (const unsigned int*)(gsrc[i] + (size_t)(c + 1) * 2048),
                    (unsigned int*)(nxt + i * 4096 + w * 1024), 16, 0, 0);
        }
        #pragma unroll
        for (int h = 0; h < 8; ++h) {
            const int ko = h * 2048 + q * 64 + ((g ^ fq) << 4);
            bf16x8 ka0 = *(const bf16x8*)(cur + ko);
            bf16x8 ka1 = *(const bf16x8*)(cur + ko + 1024);
            f32x4 z = {0.f, 0.f, 0.f, 0.f};
            f32x4 s0 = __builtin_amdgcn_mfma_f32_16x16x32_bf16(ka0, qf[h], z, 0, 0, 0);
            f32x4 s1 = __builtin_amdgcn_mfma_f32_16x16x32_bf16(ka1, qf[h], z, 0, 0, 0);
            #pragma unroll
            for (int r = 0; r < 4; ++r) {
                float e0 = EXP2(s0[r]);
                float e1 = EXP2(s1[r]);
                lacc[h] += ((wb >> (4 * g + r)) & 1u) ? e0 : 0.f;
                lacc[h] += ((wb >> (16 + 4 * g + r)) & 1u) ? e1 : 0.f;
            }
        }
        __syncthreads();
        wb = wbn;
    }
    #pragma unroll
    for (int h = 0; h < 8; ++h) {
        float v = lacc[h];
        v += __shfl_xor(v, 16);
        v += __shfl_xor(v, 32);
        if (g == 0) Lpart[(size_t)msg * 32768 + h * NN + n0 + q] = v;
    }
}

// sweep2s: r15-proven best. K+V staged via global_load_lds (64KB dbuf),
// permuted Vt -> b128 V reads at K-identical swizzled addr, 0 conflicts.
// r17 falsified direct-V (L2 latency serializes); r11/r12 falsified 8-wave.
__global__ __launch_bounds__(256, 2) void sweep2s_kernel(
    const unsigned short* __restrict__ Qb, const unsigned short* __restrict__ Kb,
    const unsigned short* __restrict__ Vt, const unsigned int* __restrict__ abit,
    const float* __restrict__ Linv, float* __restrict__ Opart,
    float* __restrict__ amean)
{
    __shared__ __align__(16) char smem[65536];
    const int nquad = blockIdx.x, msg = blockIdx.y;
    const int t = threadIdx.x;
    const int w = t >> 6, l = t & 63;
    const int g = l >> 4, q = l & 15;
    const int n0 = nquad * 64 + w * 16;
    const int m0 = msg * 512;
    const int fq = (q >> 1) & 3;

    const char* gsrc[8];
    unsigned int gstep[8];
    #pragma unroll
    for (int i = 0; i < 8; ++i) {
        int s = i * 256 + t;
        int tile = s >> 7;
        int r = (s >> 2) & 31;
        int gr = (s & 3) ^ ((r >> 1) & 3);
        if (tile < 8) {
            gsrc[i] = (const char*)Kb + (((size_t)tile * NN + m0 + r) * 64 + gr * 16);
            gstep[i] = 2048;
        } else {
            gsrc[i] = (const char*)Vt + ((((size_t)(tile - 8) * 32 + r) * NN + m0) * 2 + gr * 16);
            gstep[i] = 64;
        }
    }
    const unsigned int* abrow = abit + (size_t)(n0 + q) * 128 + msg * 16;

    bf16x8 qf[8];
    float rL[8];
    #pragma unroll
    for (int h = 0; h < 8; ++h) {
        qf[h] = *(const bf16x8*)(Qb + (((size_t)h * NN + n0 + q) << 5) + g * 8);
        rL[h] = Linv[h * NN + n0 + q];
    }
    f32x4 o[8][2];
    #pragma unroll
    for (int h = 0; h < 8; ++h) {
        o[h][0] = (f32x4){0.f, 0.f, 0.f, 0.f};
        o[h][1] = (f32x4){0.f, 0.f, 0.f, 0.f};
    }

    #pragma unroll
    for (int i = 0; i < 8; ++i)
        __builtin_amdgcn_global_load_lds((const unsigned int*)gsrc[i],
            (unsigned int*)(smem + i * 4096 + w * 1024), 16, 0, 0);
    unsigned int wb = abrow[0];
    unsigned int wbn = 0;
    __syncthreads();

    for (int c = 0; c < 16; ++c) {
        const char* cur = smem + (c & 1) * 32768;
        if (c < 15) {
            wbn = abrow[c + 1];
            char* nxt = smem + ((c & 1) ^ 1) * 32768;
            #pragma unroll
            for (int i = 0; i < 8; ++i)
                __builtin_amdgcn_global_load_lds(
                    (const unsigned int*)(gsrc[i] + (size_t)(c + 1) * gstep[i]),
                    (unsigned int*)(nxt + i * 4096 + w * 1024), 16, 0, 0);
        }
        const int mb = m0 + c * 32;
        float am[8];
        #pragma unroll
        for (int r = 0; r < 8; ++r) am[r] = 0.f;

        #pragma unroll
        for (int h = 0; h < 8; ++h) {
            const int ko = h * 2048 + q * 64 + ((g ^ fq) << 4);
            bf16x8 ka0 = *(const bf16x8*)(cur + ko);
            bf16x8 ka1 = *(const bf16x8*)(cur + ko + 1024);
            const int vo = (8 + h) * 2048 + q * 64 + ((g ^ fq) << 4);
            f16x8 lo8 = *(const f16x8*)(cur + vo);          // d = q
            f16x8 hi8 = *(const f16x8*)(cur + vo + 1024);   // d = 16+q
            f16x4 va00 = __builtin_shufflevector(lo8, lo8, 0, 1, 2, 3);
            f16x4 va10 = __builtin_shufflevector(lo8, lo8, 4, 5, 6, 7);
            f16x4 va01 = __builtin_shufflevector(hi8, hi8, 0, 1, 2, 3);
            f16x4 va11 = __builtin_shufflevector(hi8, hi8, 4, 5, 6, 7);
            f32x4 z = {0.f, 0.f, 0.f, 0.f};
            f32x4 s0 = __builtin_amdgcn_mfma_f32_16x16x32_bf16(ka0, qf[h], z, 0, 0, 0);
            f32x4 s1 = __builtin_amdgcn_mfma_f32_16x16x32_bf16(ka1, qf[h], z, 0, 0, 0);
            float pn[8];
            #pragma unroll
            for (int r = 0; r < 4; ++r) {
                float e0 = EXP2(s0[r]) * rL[h];
                float e1 = EXP2(s1[r]) * rL[h];
                pn[r]     = ((wb >> (4 * g + r)) & 1u) ? e0 : 0.f;
                pn[4 + r] = ((wb >> (16 + 4 * g + r)) & 1u) ? e1 : 0.f;
                am[r] += pn[r];
                am[4 + r] += pn[4 + r];
            }
            union { unsigned int u[2]; f16x4 v; } pA, pB;
            pA.u[0] = pkhf(pn[0], pn[1]); pA.u[1] = pkhf(pn[2], pn[3]);
            pB.u[0] = pkhf(pn[4], pn[5]); pB.u[1] = pkhf(pn[6], pn[7]);
            o[h][0] = __builtin_amdgcn_mfma_f32_16x16x16f16(va00, pA.v, o[h][0], 0, 0, 0);
            o[h][1] = __builtin_amdgcn_mfma_f32_16x16x16f16(va01, pA.v, o[h][1], 0, 0, 0);
            o[h][0] = __builtin_amdgcn_mfma_f32_16x16x16f16(va10, pB.v, o[h][0], 0, 0, 0);
            o[h][1] = __builtin_amdgcn_mfma_f32_16x16x16f16(va11, pB.v, o[h][1], 0, 0, 0);
        }
        float4 a0, a1;
        a0.x = am[0] * 0.125f; a0.y = am[1] * 0.125f;
        a0.z = am[2] * 0.125f; a0.w = am[3] * 0.125f;
        a1.x = am[4] * 0.125f; a1.y = am[5] * 0.125f;
        a1.z = am[6] * 0.125f; a1.w = am[7] * 0.125f;
        *(float4*)(amean + (size_t)(n0 + q) * NN + mb + 4 * g) = a0;
        *(float4*)(amean + (size_t)(n0 + q) * NN + mb + 16 + 4 * g) = a1;
        __syncthreads();
        wb = wbn;
    }

    float* op = Opart + ((size_t)msg * NN + n0 + q) * 256;
    #pragma unroll
    for (int h = 0; h < 8; ++h) {
        *(f32x4*)(op + h * 32 + 4 * g) = o[h][0];
        *(f32x4*)(op + h * 32 + 16 + 4 * g) = o[h][1];
    }
}

// ======================= OLD SWEEPS (path B fallback) =====================
__global__ __launch_bounds__(256, 4) void sweep1_old(
    const unsigned short* __restrict__ Qb, const unsigned short* __restrict__ Kb,
    const unsigned int* __restrict__ abit, float* __restrict__ Lpart)
{
    const int ntile = blockIdx.x, msg = blockIdx.y;
    const int t = threadIdx.x;
    const int w = t >> 6, l = t & 63;
    const int g = l >> 4, q = l & 15;
    const int ms = msg * 4 + w;
    const int n0 = ntile * 16;
    const int mbase = ms * 256;
    bf16x8 qf[8];
    #pragma unroll
    for (int h = 0; h < 8; ++h)
        qf[h] = *(const bf16x8*)(Qb + (((size_t)h * NN + n0 + q) << 5) + g * 8);
    float lacc[8];
    #pragma unroll
    for (int h = 0; h < 8; ++h) lacc[h] = 0.f;
    for (int ch = 0; ch < 8; ++ch) {
        const int mb = mbase + ch * 32;
        const unsigned int wbits = abit[(size_t)(n0 + q) * 128 + (mb >> 5)];
        #pragma unroll
        for (int h = 0; h < 8; ++h) {
            bf16x8 ka0 = *(const bf16x8*)(Kb + (((size_t)h * NN + mb + q) << 5) + g * 8);
            bf16x8 ka1 = *(const bf16x8*)(Kb + (((size_t)h * NN + mb + 16 + q) << 5) + g * 8);
            f32x4 z = {0.f, 0.f, 0.f, 0.f};
            f32x4 s0 = __builtin_amdgcn_mfma_f32_16x16x32_bf16(ka0, qf[h], z, 0, 0, 0);
            f32x4 s1 = __builtin_amdgcn_mfma_f32_16x16x32_bf16(ka1, qf[h], z, 0, 0, 0);
            #pragma unroll
            for (int r = 0; r < 4; ++r) {
                float e0 = EXP2(s0[r]);
                float e1 = EXP2(s1[r]);
                lacc[h] += ((wbits >> (4 * g + r)) & 1u) ? e0 : 0.f;
                lacc[h] += ((wbits >> (16 + 4 * g + r)) & 1u) ? e1 : 0.f;
            }
        }
    }
    #pragma unroll
    for (int h = 0; h < 8; ++h) {
        float v = lacc[h];
        v += __shfl_xor(v, 16);
        v += __shfl_xor(v, 32);
        if (g == 0) Lpart[(size_t)ms * 32768 + h * NN + n0 + q] = v;
    }
}

__global__ __launch_bounds__(256, 2) void sweep2_old(
    const unsigned short* __restrict__ Qb, const unsigned short* __restrict__ Kb,
    const unsigned short* __restrict__ Vt, const unsigned int* __restrict__ abit,
    const float* __restrict__ Linv, float* __restrict__ Opart,
    float* __restrict__ amean)
{
    __shared__ __align__(16) float Ow[2 * 16 * 260];
    const int ntile = blockIdx.x, msg = blockIdx.y;
    const int t = threadIdx.x;
    const int w = t >> 6, l = t & 63;
    const int g = l >> 4, q = l & 15;
    const int ms = msg * 4 + w;
    const int n0 = ntile * 16;
    const int mbase = ms * 256;
    const int baddr = (q + (g & 1) * 32) << 2;
    const bool hi = (g >= 2);
    bf16x8 qf[8];
    float rL[8];
    #pragma unroll
    for (int h = 0; h < 8; ++h) {
        qf[h] = *(const bf16x8*)(Qb + (((size_t)h * NN + n0 + q) << 5) + g * 8);
        rL[h] = Linv[h * NN + n0 + q];
    }
    f32x4 o[8][2];
    #pragma unroll
    for (int h = 0; h < 8; ++h) {
        o[h][0] = (f32x4){0.f, 0.f, 0.f, 0.f};
        o[h][1] = (f32x4){0.f, 0.f, 0.f, 0.f};
    }
    for (int ch = 0; ch < 8; ++ch) {
        const int mb = mbase + ch * 32;
        const unsigned int wbits = abit[(size_t)(n0 + q) * 128 + (mb >> 5)];
        float am[8];
        #pragma unroll
        for (int r = 0; r < 8; ++r) am[r] = 0.f;
        #pragma unroll
        for (int h = 0; h < 8; ++h) {
            bf16x8 ka0 = *(const bf16x8*)(Kb + (((size_t)h * NN + mb + q) << 5) + g * 8);
            bf16x8 ka1 = *(const bf16x8*)(Kb + (((size_t)h * NN + mb + 16 + q) << 5) + g * 8);
            f32x4 z = {0.f, 0.f, 0.f, 0.f};
            f32x4 s0 = __builtin_amdgcn_mfma_f32_16x16x32_bf16(ka0, qf[h], z, 0, 0, 0);
            f32x4 s1 = __builtin_amdgcn_mfma_f32_16x16x32_bf16(ka1, qf[h], z, 0, 0, 0);
            float pn[8];
            #pragma unroll
            for (int r = 0; r < 4; ++r) {
                float e0 = EXP2(s0[r]) * rL[h];
                float e1 = EXP2(s1[r]) * rL[h];
                pn[r]     = ((wbits >> (4 * g + r)) & 1u) ? e0 : 0.f;
                pn[4 + r] = ((wbits >> (16 + 4 * g + r)) & 1u) ? e1 : 0.f;
                am[r] += pn[r];
                am[4 + r] += pn[4 + r];
            }
            unsigned int pk0 = pkbf(pn[0], pn[1]);
            unsigned int pk1 = pkbf(pn[2], pn[3]);
            unsigned int pk2 = pkbf(pn[4], pn[5]);
            unsigned int pk3 = pkbf(pn[6], pn[7]);
            int r0lo = __builtin_amdgcn_ds_bpermute(baddr,      (int)pk0);
            int r0hi = __builtin_amdgcn_ds_bpermute(baddr,      (int)pk2);
            int r1lo = __builtin_amdgcn_ds_bpermute(baddr,      (int)pk1);
            int r1hi = __builtin_amdgcn_ds_bpermute(baddr,      (int)pk3);
            int r2lo = __builtin_amdgcn_ds_bpermute(baddr + 64, (int)pk0);
            int r2hi = __builtin_amdgcn_ds_bpermute(baddr + 64, (int)pk2);
            int r3lo = __builtin_amdgcn_ds_bpermute(baddr + 64, (int)pk1);
            int r3hi = __builtin_amdgcn_ds_bpermute(baddr + 64, (int)pk3);
            union { unsigned int u[4]; bf16x8 v; } pu;
            pu.u[0] = (unsigned int)(hi ? r0hi : r0lo);
            pu.u[1] = (unsigned int)(hi ? r1hi : r1lo);
            pu.u[2] = (unsigned int)(hi ? r2hi : r2lo);
            pu.u[3] = (unsigned int)(hi ? r3hi : r3lo);
            bf16x8 va0 = *(const bf16x8*)(Vt + ((size_t)(h * 32 + q)) * NN + mb + g * 8);
            bf16x8 va1 = *(const bf16x8*)(Vt + ((size_t)(h * 32 + 16 + q)) * NN + mb + g * 8);
            o[h][0] = __builtin_amdgcn_mfma_f32_16x16x32_bf16(va0, pu.v, o[h][0], 0, 0, 0);
            o[h][1] = __builtin_amdgcn_mfma_f32_16x16x32_bf16(va1, pu.v, o[h][1], 0, 0, 0);
        }
        float4 a0, a1;
        a0.x = am[0] * 0.125f; a0.y = am[1] * 0.125f;
        a0.z = am[2] * 0.125f; a0.w = am[3] * 0.125f;
        a1.x = am[4] * 0.125f; a1.y = am[5] * 0.125f;
        a1.z = am[6] * 0.125f; a1.w = am[7] * 0.125f;
        *(float4*)(amean + (size_t)(n0 + q) * NN + mb + 4 * g) = a0;
        *(float4*)(amean + (size_t)(n0 + q) * NN + mb + 16 + 4 * g) = a1;
    }
    if (w < 2) {
        #pragma unroll
        for (int h = 0; h < 8; ++h)
            #pragma unroll
            for (int dt = 0; dt < 2; ++dt)
                *(f32x4*)&Ow[w * 4160 + q * 260 + h * 32 + dt * 16 + 4 * g] = o[h][dt];
    }
    __syncthreads();
    if (w >= 2) {
        #pragma unroll
        for (int h = 0; h < 8; ++h)
            #pragma unroll
            for (int dt = 0; dt < 2; ++dt) {
                f32x4* p = (f32x4*)&Ow[(w - 2) * 4160 + q * 260 + h * 32 + dt * 16 + 4 * g];
                *p = *p + o[h][dt];
            }
    }
    __syncthreads();
    for (int i = t; i < 4096; i += 256) {
        int n = i >> 8, c2 = i & 255;
        float v = Ow[n * 260 + c2] + Ow[4160 + n * 260 + c2];
        Opart[((size_t)msg * NN + n0 + n) * 256 + c2] = v;
    }
}

// ---------------- Linv ----------------------------------------------------
__global__ __launch_bounds__(256) void linv_kernel(
    const float* __restrict__ Lpart, float* __restrict__ Linv, int nms)
{
    int i = blockIdx.x * 256 + threadIdx.x;
    float s = 0.f;
    for (int ms = 0; ms < nms; ++ms) s += Lpart[(size_t)ms * 32768 + i];
    Linv[i] = 1.0f / s;
}

// -------- finalize: routed = (sum_ms Opart) @ Wo + bo ---------------------
__global__ __launch_bounds__(256) void final_kernel(
    const float* __restrict__ Opart, const float* __restrict__ Wo,
    const float* __restrict__ bo, float* __restrict__ routed, int nms)
{
    __shared__ __align__(16) float Osum[16 * 260];
    __shared__ __align__(16) float WoT[32 * 260];
    const int nb = blockIdx.x, t = threadIdx.x;
    for (int i4 = t; i4 < 2048; i4 += 256) {
        int k = i4 >> 3, j4b = i4 & 7;
        float4 v = *(const float4*)(Wo + k * 32 + j4b * 4);
        WoT[(j4b * 4 + 0) * 260 + k] = v.x;
        WoT[(j4b * 4 + 1) * 260 + k] = v.y;
        WoT[(j4b * 4 + 2) * 260 + k] = v.z;
        WoT[(j4b * 4 + 3) * 260 + k] = v.w;
    }
    for (int i = t; i < 4096; i += 256) {
        int r = i >> 8, c = i & 255;
        const float* ap = Opart + ((size_t)(nb * 16 + r)) * 256 + c;
        float s = 0.f;
        for (int ms = 0; ms < nms; ++ms) s += ap[(size_t)ms * 1048576];
        Osum[r * 260 + c] = s;
    }
    __syncthreads();
    const int rh = t >> 5, j = t & 31;
    const float bj = bo[j];
    #pragma unroll
    for (int rr = 0; rr < 2; ++rr) {
        int r = rh * 2 + rr;
        float a0 = 0.f, a1 = 0.f;
        #pragma unroll
        for (int i4 = 0; i4 < 64; i4 += 2) {
            float4 ov = *(const float4*)&Osum[r * 260 + i4 * 4];
            float4 wv = *(const float4*)&WoT[j * 260 + i4 * 4];
            a0 += ov.x * wv.x + ov.y * wv.y + ov.z * wv.z + ov.w * wv.w;
            float4 ov2 = *(const float4*)&Osum[r * 260 + i4 * 4 + 4];
            float4 wv2 = *(const float4*)&WoT[j * 260 + i4 * 4 + 4];
            a1 += ov2.x * wv2.x + ov2.y * wv2.y + ov2.z * wv2.z + ov2.w * wv2.w;
        }
        routed[(size_t)(nb * 16 + r) * 32 + j] = a0 + a1 + bj;
    }
}

extern "C" void kernel_launch(void* const* d_in, const int* in_sizes, int n_in,
                              void* d_out, int out_size, void* d_ws, size_t ws_size,
                              hipStream_t stream) {
    const float* nf  = (const float*)d_in[0];
    const float* msg = (const float*)d_in[1];
    const int*   adj = (const int*)d_in[2];
    const float* Wq  = (const float*)d_in[3];
    const float* bq  = (const float*)d_in[4];
    const float* Wk  = (const float*)d_in[5];
    const float* bk  = (const float*)d_in[6];
    const float* Wv  = (const float*)d_in[7];
    const float* bv  = (const float*)d_in[8];
    const float* Wo  = (const float*)d_in[9];
    const float* bo  = (const float*)d_in[10];

    float* routed = (float*)d_out;
    float* amean  = (float*)d_out + (size_t)NN * MD;
    float* ws = (float*)d_ws;

    const bool bigws = (ws_size >= 43122688ull);

    if (bigws) {
        float* Vf = ws;                                     // dead before sweep2s
        unsigned short* NFb = (unsigned short*)(ws + 2097152);
        unsigned short* Wt  = (unsigned short*)(ws + 2621440);
        float* Opart = ws;                                  // 8 x 1M floats
        unsigned short* Qb = (unsigned short*)(ws + 8388608);
        unsigned short* Kb = (unsigned short*)(ws + 8912896);
        unsigned short* Vt = (unsigned short*)(ws + 9437184);
        unsigned int*   ab32 = (unsigned int*)(ws + 9961472);
        float* Lpart = ws + 10485760;
        float* Linv  = ws + 10747904;

        prep_kernel<<<544, 256, 0, stream>>>(nf, Wq, Wk, NFb, Wt);
        proj_mfma<<<256, 256, 0, stream>>>(NFb, Wt, bq, bk, Qb, Kb);
        proj_v<<<128, 256, 0, stream>>>(msg, Wv, bv, Vf);
        abit_kernel<<<1024, 256, 0, stream>>>(adj, ab32);
        pack_vt<<<256, 256, 0, stream>>>(Vf, Vt, 1);
        sweep1s_kernel<<<dim3(64, 8), 256, 0, stream>>>(Qb, Kb, ab32, Lpart);
        linv_kernel<<<128, 256, 0, stream>>>(Lpart, Linv, 8);
        sweep2s_kernel<<<dim3(64, 8), 256, 0, stream>>>(Qb, Kb, Vt, ab32, Linv, Opart, amean);
        final_kernel<<<256, 256, 0, stream>>>(Opart, Wo, bo, routed, 8);
    } else {
        float* Vf = ws;
        unsigned short* NFb = (unsigned short*)(ws + 2097152);
        unsigned short* Wt  = (unsigned short*)(ws + 2621440);
        float* Opart = ws;                                  // 4 x 1M floats
        unsigned short* Qb = (unsigned short*)(ws + 4194304);
        unsigned short* Kb = (unsigned short*)(ws + 4718592);
        unsigned short* Vt = (unsigned short*)(ws + 5242880);
        unsigned int*   ab32 = (unsigned int*)(ws + 5767168);
        float* Lpart = ws + 6291456;
        float* Linv  = ws + 6815744;

        prep_kernel<<<544, 256, 0, stream>>>(nf, Wq, Wk, NFb, Wt);
        proj_mfma<<<256, 256, 0, stream>>>(NFb, Wt, bq, bk, Qb, Kb);
        proj_v<<<128, 256, 0, stream>>>(msg, Wv, bv, Vf);
        abit_kernel<<<1024, 256, 0, stream>>>(adj, ab32);
        pack_vt<<<256, 256, 0, stream>>>(Vf, Vt, 0);
        sweep1_old<<<dim3(256, 4), 256, 0, stream>>>(Qb, Kb, ab32, Lpart);
        linv_kernel<<<128, 256, 0, stream>>>(Lpart, Linv, 16);
        sweep2_old<<<dim3(256, 4), 256, 0, stream>>>(Qb, Kb, Vt, ab32, Linv, Opart, amean);
        final_kernel<<<256, 256, 0, stream>>>(Opart, Wo, bo, routed, 4);
    }
}